// Round 11
// baseline (2158.606 us; speedup 1.0000x reference)
//
#include <hip/hip_runtime.h>
#include <math.h>

#define FLAG_RELU 1
#define FLAG_BIAS 2
#define FLAG_ACC  4

static constexpr int BB   = 2;
static constexpr int N0   = 10000;
static constexpr int DIN  = 1024;
static constexpr int D    = 512;
static constexpr int NH   = 8;
static constexpr int DH   = 64;
static constexpr int MM   = 256;
static constexpr int SEQ  = 10240;
static constexpr int PADR = 239;
static constexpr int NTOK = 10001;
static constexpr int LL   = 40;
static constexpr int NCH  = 32;   // flash chunks per slab (32: partials+Ksplit fit in dead S3)
static constexpr float EPS_ = 1e-5f;

typedef short short8v __attribute__((ext_vector_type(8)));
typedef float f32x4 __attribute__((ext_vector_type(4)));

__device__ __forceinline__ void atomicMaxPosF(float* addr, float v) {
    atomicMax((unsigned int*)addr, __float_as_uint(v));
}
__device__ __forceinline__ ushort f2bf(float f) {
    unsigned u = __float_as_uint(f);
    return (ushort)((u + 0x7FFFu + ((u >> 16) & 1u)) >> 16);
}
__device__ __forceinline__ float bf2f(ushort h) {
    return __uint_as_float(((unsigned)h) << 16);
}
// packed fp32x2 -> bf16x2 (RNE, identical to f2bf). low16 = cvt(s0).
__device__ __forceinline__ unsigned cvt_pk_bf16(float s0, float s1) {
    unsigned r;
    asm("v_cvt_pk_bf16_f32 %0, %1, %2" : "=v"(r) : "v"(s0), "v"(s1));
    return r;
}
struct bfs4 { unsigned h01, h23, l01, l23; };
__device__ __forceinline__ bfs4 split4pk(float4 f) {
    bfs4 o;
    o.h01 = cvt_pk_bf16(f.x, f.y);
    o.h23 = cvt_pk_bf16(f.z, f.w);
    float hx = __uint_as_float(o.h01 << 16);
    float hy = __uint_as_float(o.h01 & 0xFFFF0000u);
    float hz = __uint_as_float(o.h23 << 16);
    float hw = __uint_as_float(o.h23 & 0xFFFF0000u);
    o.l01 = cvt_pk_bf16(f.x - hx, f.y - hy);
    o.l23 = cvt_pk_bf16(f.z - hz, f.w - hw);
    return o;
}
__device__ __forceinline__ void split8r(const float* p, short8v& h, short8v& l) {
    float4 f0 = *(const float4*)p, f1 = *(const float4*)(p + 4);
    bfs4 a = split4pk(f0), b = split4pk(f1);
    uint4 hu = make_uint4(a.h01, a.h23, b.h01, b.h23);
    uint4 lu = make_uint4(a.l01, a.l23, b.l01, b.l23);
    h = *(short8v*)&hu; l = *(short8v*)&lu;
}

// ------------------------------------------------------- MFMA GEMM 128x128
__global__ __launch_bounds__(256)
void mgemm128(const float* __restrict__ A, int lda, long long sAz,
              const ushort* __restrict__ BtH, const ushort* __restrict__ BtL, int ldbt,
              float* __restrict__ C, int ldc, long long sCz, const float* __restrict__ bias,
              int M, int N, int K, int flags, int qcols, float qscale)
{
    __shared__ ushort AsH[4*128*8], AsL[4*128*8], BsH[4*128*8], BsL[4*128*8]; // 32 KB
    A += (size_t)blockIdx.z * sAz;
    C += (size_t)blockIdx.z * sCz;
    int t = threadIdx.x;
    int m0 = blockIdx.y * 128, n0 = blockIdx.x * 128;
    int w = t >> 6, lane = t & 63, q = lane >> 4, r = lane & 15;
    int wm = w >> 1, wn = w & 1;
    f32x4 acc[4][4];
    #pragma unroll
    for (int i = 0; i < 4; i++)
        #pragma unroll
        for (int j = 0; j < 4; j++) acc[i][j] = (f32x4){0.f,0.f,0.f,0.f};

    int srow = t >> 1, scg = (t & 1) * 16;
    int qg = (t & 1) * 2;
    int gm = m0 + srow;
    float4 pa0, pa1, pa2, pa3;
    uint4  pb0, pb1, pb2, pb3;
    {
        pa0 = pa1 = pa2 = pa3 = make_float4(0,0,0,0);
        if (gm < M) {
            const float* ap = A + (size_t)gm * lda + scg;
            pa0 = *(const float4*)(ap);   pa1 = *(const float4*)(ap+4);
            pa2 = *(const float4*)(ap+8); pa3 = *(const float4*)(ap+12);
        }
        size_t gb = (size_t)(n0 + srow) * ldbt + scg;
        pb0 = *(const uint4*)(BtH + gb); pb1 = *(const uint4*)(BtH + gb + 8);
        pb2 = *(const uint4*)(BtL + gb); pb3 = *(const uint4*)(BtL + gb + 8);
    }
    for (int k0 = 0; k0 < K; k0 += 32) {
        {
            bfs4 s0 = split4pk(pa0), s1 = split4pk(pa1);
            bfs4 s2 = split4pk(pa2), s3 = split4pk(pa3);
            *(uint4*)&AsH[(qg  )*1024 + srow*8] = make_uint4(s0.h01, s0.h23, s1.h01, s1.h23);
            *(uint4*)&AsH[(qg+1)*1024 + srow*8] = make_uint4(s2.h01, s2.h23, s3.h01, s3.h23);
            *(uint4*)&AsL[(qg  )*1024 + srow*8] = make_uint4(s0.l01, s0.l23, s1.l01, s1.l23);
            *(uint4*)&AsL[(qg+1)*1024 + srow*8] = make_uint4(s2.l01, s2.l23, s3.l01, s3.l23);
            *(uint4*)&BsH[(qg  )*1024 + srow*8] = pb0;
            *(uint4*)&BsH[(qg+1)*1024 + srow*8] = pb1;
            *(uint4*)&BsL[(qg  )*1024 + srow*8] = pb2;
            *(uint4*)&BsL[(qg+1)*1024 + srow*8] = pb3;
        }
        __syncthreads();
        if (k0 + 32 < K) {
            pa0 = pa1 = pa2 = pa3 = make_float4(0,0,0,0);
            if (gm < M) {
                const float* ap = A + (size_t)gm * lda + k0 + 32 + scg;
                pa0 = *(const float4*)(ap);   pa1 = *(const float4*)(ap+4);
                pa2 = *(const float4*)(ap+8); pa3 = *(const float4*)(ap+12);
            }
            size_t gb = (size_t)(n0 + srow) * ldbt + k0 + 32 + scg;
            pb0 = *(const uint4*)(BtH + gb); pb1 = *(const uint4*)(BtH + gb + 8);
            pb2 = *(const uint4*)(BtL + gb); pb3 = *(const uint4*)(BtL + gb + 8);
        }
        short8v ah[4], al[4];
        #pragma unroll
        for (int mi = 0; mi < 4; mi++) {
            int row = wm*64 + mi*16 + r;
            ah[mi] = *(const short8v*)&AsH[q*1024 + row*8];
            al[mi] = *(const short8v*)&AsL[q*1024 + row*8];
        }
        #pragma unroll
        for (int ni = 0; ni < 4; ni++) {
            int col = wn*64 + ni*16 + r;
            short8v bh = *(const short8v*)&BsH[q*1024 + col*8];
            short8v bl = *(const short8v*)&BsL[q*1024 + col*8];
            #pragma unroll
            for (int mi = 0; mi < 4; mi++) {
                acc[mi][ni] = __builtin_amdgcn_mfma_f32_16x16x32_bf16(ah[mi], bh, acc[mi][ni], 0,0,0);
                acc[mi][ni] = __builtin_amdgcn_mfma_f32_16x16x32_bf16(ah[mi], bl, acc[mi][ni], 0,0,0);
                acc[mi][ni] = __builtin_amdgcn_mfma_f32_16x16x32_bf16(al[mi], bh, acc[mi][ni], 0,0,0);
            }
        }
        __syncthreads();
    }
    #pragma unroll
    for (int mi = 0; mi < 4; mi++)
        #pragma unroll
        for (int ni = 0; ni < 4; ni++) {
            int gcol = n0 + wn*64 + ni*16 + r;
            float qs = (gcol < qcols) ? qscale : 1.f;
            float bv = (flags & FLAG_BIAS) ? bias[gcol] : 0.f;
            #pragma unroll
            for (int rg = 0; rg < 4; rg++) {
                int grow = m0 + wm*64 + mi*16 + q*4 + rg;
                if (grow >= M) continue;
                float v = acc[mi][ni][rg] * qs + bv;
                if (flags & FLAG_RELU) v = fmaxf(v, 0.f);
                float* cp = C + (size_t)grow * ldc + gcol;
                if (flags & FLAG_ACC) v += *cp;
                *cp = v;
            }
        }
}

// ----------------------------------- MFMA GEMM 128x128, BOTH operands pre-split
// For the QKV projection: A = LN pre-split by ln_pad (bit-identical to the
// split mgemm128 would apply to the same fp32 values). Staging is pure uint4
// copies -> removes the 12x-redundant per-n-block split VALU work.
__global__ __launch_bounds__(256)
void mgemm128bb(const ushort* __restrict__ AtH, const ushort* __restrict__ AtL, int lda,
                const ushort* __restrict__ BtH, const ushort* __restrict__ BtL, int ldbt,
                float* __restrict__ C, int ldc,
                int M, int N, int K, int qcols, float qscale)
{
    __shared__ ushort AsH[4*128*8], AsL[4*128*8], BsH[4*128*8], BsL[4*128*8]; // 32 KB
    int t = threadIdx.x;
    int m0 = blockIdx.y * 128, n0 = blockIdx.x * 128;
    int w = t >> 6, lane = t & 63, q = lane >> 4, r = lane & 15;
    int wm = w >> 1, wn = w & 1;
    f32x4 acc[4][4];
    #pragma unroll
    for (int i = 0; i < 4; i++)
        #pragma unroll
        for (int j = 0; j < 4; j++) acc[i][j] = (f32x4){0.f,0.f,0.f,0.f};

    int srow = t >> 1, scg = (t & 1) * 16;
    int qg = (t & 1) * 2;
    size_t ga = (size_t)(m0 + srow) * lda + scg;
    size_t gb = (size_t)(n0 + srow) * ldbt + scg;
    uint4 pa0, pa1, pa2, pa3, pb0, pb1, pb2, pb3;
    {
        pa0 = *(const uint4*)(AtH + ga); pa1 = *(const uint4*)(AtH + ga + 8);
        pa2 = *(const uint4*)(AtL + ga); pa3 = *(const uint4*)(AtL + ga + 8);
        pb0 = *(const uint4*)(BtH + gb); pb1 = *(const uint4*)(BtH + gb + 8);
        pb2 = *(const uint4*)(BtL + gb); pb3 = *(const uint4*)(BtL + gb + 8);
    }
    for (int k0 = 0; k0 < K; k0 += 32) {
        {
            *(uint4*)&AsH[(qg  )*1024 + srow*8] = pa0;
            *(uint4*)&AsH[(qg+1)*1024 + srow*8] = pa1;
            *(uint4*)&AsL[(qg  )*1024 + srow*8] = pa2;
            *(uint4*)&AsL[(qg+1)*1024 + srow*8] = pa3;
            *(uint4*)&BsH[(qg  )*1024 + srow*8] = pb0;
            *(uint4*)&BsH[(qg+1)*1024 + srow*8] = pb1;
            *(uint4*)&BsL[(qg  )*1024 + srow*8] = pb2;
            *(uint4*)&BsL[(qg+1)*1024 + srow*8] = pb3;
        }
        __syncthreads();
        if (k0 + 32 < K) {
            size_t ga2 = ga + k0 + 32;
            size_t gb2 = gb + k0 + 32;
            pa0 = *(const uint4*)(AtH + ga2); pa1 = *(const uint4*)(AtH + ga2 + 8);
            pa2 = *(const uint4*)(AtL + ga2); pa3 = *(const uint4*)(AtL + ga2 + 8);
            pb0 = *(const uint4*)(BtH + gb2); pb1 = *(const uint4*)(BtH + gb2 + 8);
            pb2 = *(const uint4*)(BtL + gb2); pb3 = *(const uint4*)(BtL + gb2 + 8);
        }
        short8v ah[4], al[4];
        #pragma unroll
        for (int mi = 0; mi < 4; mi++) {
            int row = wm*64 + mi*16 + r;
            ah[mi] = *(const short8v*)&AsH[q*1024 + row*8];
            al[mi] = *(const short8v*)&AsL[q*1024 + row*8];
        }
        #pragma unroll
        for (int ni = 0; ni < 4; ni++) {
            int col = wn*64 + ni*16 + r;
            short8v bh = *(const short8v*)&BsH[q*1024 + col*8];
            short8v bl = *(const short8v*)&BsL[q*1024 + col*8];
            #pragma unroll
            for (int mi = 0; mi < 4; mi++) {
                acc[mi][ni] = __builtin_amdgcn_mfma_f32_16x16x32_bf16(ah[mi], bh, acc[mi][ni], 0,0,0);
                acc[mi][ni] = __builtin_amdgcn_mfma_f32_16x16x32_bf16(ah[mi], bl, acc[mi][ni], 0,0,0);
                acc[mi][ni] = __builtin_amdgcn_mfma_f32_16x16x32_bf16(al[mi], bh, acc[mi][ni], 0,0,0);
            }
        }
        __syncthreads();
    }
    #pragma unroll
    for (int mi = 0; mi < 4; mi++)
        #pragma unroll
        for (int ni = 0; ni < 4; ni++) {
            int gcol = n0 + wn*64 + ni*16 + r;
            float qs = (gcol < qcols) ? qscale : 1.f;
            #pragma unroll
            for (int rg = 0; rg < 4; rg++) {
                int grow = m0 + wm*64 + mi*16 + q*4 + rg;
                C[(size_t)grow * ldc + gcol] = acc[mi][ni][rg] * qs;
            }
        }
}

// ------------------------------------------------------- MFMA batched 32x32
// Small-tile batched GEMM for the Newton-Schulz chain + WB GEMM (R6 win:
// 4x the block count of the 64x64 variant -> 4x occupancy on these small
// latency-bound GEMMs).
__global__ __launch_bounds__(256)
void mbgemm32(const float* __restrict__ Abase, long long sAz, int lda,
              const ushort* __restrict__ BtH, const ushort* __restrict__ BtL,
              long long sB, int ldb,
              float* __restrict__ Cbase, long long sC, int ldc,
              ushort* __restrict__ eTH, ushort* __restrict__ eTL, long long sT, int ldct,
              int K, float dg, float bsc, float osc)
{
    __shared__ ushort AsH[4*32*8], AsL[4*32*8], BsH[4*32*8], BsL[4*32*8]; // 8 KB
    int g = blockIdx.z;
    const float* A = Abase + (size_t)g * sAz;
    float* C = Cbase ? (Cbase + (size_t)g * sC) : nullptr;
    int t = threadIdx.x;
    int m0 = blockIdx.y * 32, n0 = blockIdx.x * 32;
    int w = t >> 6, lane = t & 63, q = lane >> 4, r = lane & 15;
    int wm = w >> 1, wn = w & 1;
    f32x4 acc = (f32x4){0.f,0.f,0.f,0.f};

    int srow = t >> 3, scg = (t & 7) * 4;
    int qg = scg >> 3, qo = scg & 4;
    float4 pa;
    uint2 pbh, pbl;
    {
        pa = *(const float4*)(A + (size_t)(m0 + srow) * lda + scg);
        size_t gb = (size_t)g*sB + (size_t)(n0 + srow) * ldb + scg;
        pbh = *(const uint2*)(BtH + gb); pbl = *(const uint2*)(BtL + gb);
    }
    for (int k0 = 0; k0 < K; k0 += 32) {
        {
            bfs4 s = split4pk(pa);
            *(uint2*)&AsH[qg*256 + srow*8 + qo] = make_uint2(s.h01, s.h23);
            *(uint2*)&AsL[qg*256 + srow*8 + qo] = make_uint2(s.l01, s.l23);
            *(uint2*)&BsH[qg*256 + srow*8 + qo] = pbh;
            *(uint2*)&BsL[qg*256 + srow*8 + qo] = pbl;
        }
        __syncthreads();
        if (k0 + 32 < K) {
            pa = *(const float4*)(A + (size_t)(m0 + srow) * lda + k0 + 32 + scg);
            size_t gb = (size_t)g*sB + (size_t)(n0 + srow) * ldb + k0 + 32 + scg;
            pbh = *(const uint2*)(BtH + gb); pbl = *(const uint2*)(BtL + gb);
        }
        short8v ah = *(const short8v*)&AsH[q*256 + (wm*16 + r)*8];
        short8v al = *(const short8v*)&AsL[q*256 + (wm*16 + r)*8];
        short8v bh = *(const short8v*)&BsH[q*256 + (wn*16 + r)*8];
        short8v bl = *(const short8v*)&BsL[q*256 + (wn*16 + r)*8];
        acc = __builtin_amdgcn_mfma_f32_16x16x32_bf16(ah, bh, acc, 0,0,0);
        acc = __builtin_amdgcn_mfma_f32_16x16x32_bf16(ah, bl, acc, 0,0,0);
        acc = __builtin_amdgcn_mfma_f32_16x16x32_bf16(al, bh, acc, 0,0,0);
        __syncthreads();
    }
    bool dgnz = (dg != 0.f);
    int gm0 = m0 + wm*16 + q*4;
    int gn  = n0 + wn*16 + r;
    float v[4];
    #pragma unroll
    for (int rg = 0; rg < 4; rg++) {
        float u = bsc * acc[rg];
        if (dgnz) u += dg * A[(size_t)(gm0+rg) * lda + gn];
        v[rg] = osc * u;
    }
    if (C) {
        #pragma unroll
        for (int rg = 0; rg < 4; rg++)
            C[(size_t)(gm0+rg) * ldc + gn] = v[rg];
    }
    if (eTH) {
        unsigned h01 = cvt_pk_bf16(v[0], v[1]);
        unsigned h23 = cvt_pk_bf16(v[2], v[3]);
        float h0 = __uint_as_float(h01 << 16);
        float h1 = __uint_as_float(h01 & 0xFFFF0000u);
        float h2 = __uint_as_float(h23 << 16);
        float h3 = __uint_as_float(h23 & 0xFFFF0000u);
        unsigned l01 = cvt_pk_bf16(v[0] - h0, v[1] - h1);
        unsigned l23 = cvt_pk_bf16(v[2] - h2, v[3] - h3);
        size_t to = (size_t)g * sT + (size_t)gn * ldct + gm0;
        *(uint2*)(eTH + to) = make_uint2(h01, h23);
        *(uint2*)(eTL + to) = make_uint2(l01, l23);
    }
}

// ------------------------------- pre-split K part of QKV -> [g][tok][64] bf16
// Removes strided fp32 K loads + split VALU from a3v_flash's critical path
// (same split4pk on the same fp32 values -> bit-identical MFMA inputs).
__global__ __launch_bounds__(256)
void ksplit(const float* __restrict__ qkv, ushort* __restrict__ oh, ushort* __restrict__ ol)
{
    int g = blockIdx.y, b = g >> 3, h = g & 7;
    int tok0 = blockIdx.x * 16;
    int t = threadIdx.x;
    int tl = t >> 4, dq = (t & 15) * 4;
    const float* src = qkv + ((size_t)b*SEQ + tok0 + tl) * 1536 + D + h*DH + dq;
    float4 v = *(const float4*)src;
    bfs4 s = split4pk(v);
    size_t o = ((size_t)g*SEQ + tok0 + tl) * DH + dq;
    *(uint2*)(oh + o) = make_uint2(s.h01, s.h23);
    *(uint2*)(ol + o) = make_uint2(s.l01, s.l23);
}

// ---------------------------------------------- flash A3V (S3 never stored)
// R8: replaced the S3 materialize+maxsum+atomic-GEMM pipeline (-46us).
// R9: NCH 16->32 (-32us). R11: K pre-split (ksplit) -> S-tile loop does pure
// bf16 loads for K (was strided fp32 + split8r in the serial path).
__global__ __launch_bounds__(256)
void a3v_flash(const float* __restrict__ ql,
               const ushort* __restrict__ ksH, const ushort* __restrict__ ksL,
               const ushort* __restrict__ vtH, const ushort* __restrict__ vtL,
               float* __restrict__ PO, float* __restrict__ PM, float* __restrict__ PL)
{
    constexpr int LP  = 72;              // 64 + 8 pad (a1_fused's scheme)
    constexpr int CHT = SEQ / NCH;       // 320
    __shared__ ushort PcH[64*LP], PcL[64*LP];   // 9.2 KB each
    __shared__ float redm[2][64], reds[2][64];
    __shared__ float mrun[64], lrun[64];
    int ch = blockIdx.x, my = blockIdx.y, g = blockIdx.z;
    int t = threadIdx.x;
    int w = t >> 6, lane = t & 63, q = lane >> 4, r = lane & 15;
    int wm = w >> 1, wn = w & 1;

    if (t < 64) { mrun[t] = -3.4e38f; lrun[t] = 0.f; }

    // hoisted QL A-fragments (rows wm*32+mi*16+r, k = k0*32+q*8)
    short8v qh[2][2], qlo[2][2];
    #pragma unroll
    for (int mi = 0; mi < 2; mi++)
        #pragma unroll
        for (int k0 = 0; k0 < 2; k0++) {
            const float* ap = ql + ((size_t)g*MM + my*64 + wm*32 + mi*16 + r) * DH
                            + k0*32 + q*8;
            split8r(ap, qh[mi][k0], qlo[mi][k0]);
        }
    const ushort* kH = ksH + (size_t)g*SEQ*DH;
    const ushort* kL = ksL + (size_t)g*SEQ*DH;
    const ushort* vH = vtH + (size_t)g*DH*SEQ;
    const ushort* vL = vtL + (size_t)g*DH*SEQ;
    f32x4 oacc[2][2];
    #pragma unroll
    for (int i = 0; i < 2; i++)
        #pragma unroll
        for (int j = 0; j < 2; j++) oacc[i][j] = (f32x4){0.f,0.f,0.f,0.f};
    __syncthreads();

    for (int tt = 0; tt < CHT/64; tt++) {
        int tok0 = ch*CHT + tt*64;
        // ---- S tile: 64 rows x 64 tokens (K from pre-split buffer)
        f32x4 sacc[2][2];
        #pragma unroll
        for (int i = 0; i < 2; i++)
            #pragma unroll
            for (int j = 0; j < 2; j++) sacc[i][j] = (f32x4){0.f,0.f,0.f,0.f};
        #pragma unroll
        for (int k0 = 0; k0 < 2; k0++)
            #pragma unroll
            for (int ni = 0; ni < 2; ni++) {
                size_t ko = ((size_t)(tok0 + wn*32 + ni*16 + r))*DH + k0*32 + q*8;
                short8v bh = *(const short8v*)(kH + ko);
                short8v bl = *(const short8v*)(kL + ko);
                #pragma unroll
                for (int mi = 0; mi < 2; mi++) {
                    sacc[mi][ni] = __builtin_amdgcn_mfma_f32_16x16x32_bf16(qh[mi][k0], bh, sacc[mi][ni], 0,0,0);
                    sacc[mi][ni] = __builtin_amdgcn_mfma_f32_16x16x32_bf16(qh[mi][k0], bl, sacc[mi][ni], 0,0,0);
                    sacc[mi][ni] = __builtin_amdgcn_mfma_f32_16x16x32_bf16(qlo[mi][k0], bh, sacc[mi][ni], 0,0,0);
                }
            }
        // ---- tile row max
        #pragma unroll
        for (int mi = 0; mi < 2; mi++)
            #pragma unroll
            for (int rg = 0; rg < 4; rg++) {
                float m = fmaxf(sacc[mi][0][rg], sacc[mi][1][rg]);
                for (int o = 8; o > 0; o >>= 1) m = fmaxf(m, __shfl_xor(m, o));
                if (r == 0) redm[wn][wm*32 + mi*16 + q*4 + rg] = m;
            }
        __syncthreads();
        // ---- online update: P, partial sums, oacc rescale
        float scv[2][4], mnv[2][4];
        #pragma unroll
        for (int mi = 0; mi < 2; mi++)
            #pragma unroll
            for (int rg = 0; rg < 4; rg++) {
                int row = wm*32 + mi*16 + q*4 + rg;
                float tm = fmaxf(redm[0][row], redm[1][row]);
                float mo = mrun[row];
                float mn = fmaxf(mo, tm);
                float sc = __expf(mo - mn);
                scv[mi][rg] = sc; mnv[mi][rg] = mn;
                float e0 = __expf(sacc[mi][0][rg] - mn);
                float e1 = __expf(sacc[mi][1][rg] - mn);
                float s = e0 + e1;
                unsigned h01 = cvt_pk_bf16(e0, e1);
                float r0 = __uint_as_float(h01 << 16);
                float r1 = __uint_as_float(h01 & 0xFFFF0000u);
                unsigned l01 = cvt_pk_bf16(e0 - r0, e1 - r1);
                int cb = row*LP + wn*32 + r;
                PcH[cb     ] = (ushort)h01;
                PcH[cb + 16] = (ushort)(h01 >> 16);
                PcL[cb     ] = (ushort)l01;
                PcL[cb + 16] = (ushort)(l01 >> 16);
                oacc[mi][0][rg] *= sc;
                oacc[mi][1][rg] *= sc;
                for (int o = 8; o > 0; o >>= 1) s += __shfl_xor(s, o);
                if (r == 0) reds[wn][row] = s;
            }
        __syncthreads();
        if (wn == 0 && r == 0) {
            #pragma unroll
            for (int mi = 0; mi < 2; mi++)
                #pragma unroll
                for (int rg = 0; rg < 4; rg++) {
                    int row = wm*32 + mi*16 + q*4 + rg;
                    lrun[row] = lrun[row]*scv[mi][rg] + reds[0][row] + reds[1][row];
                    mrun[row] = mnv[mi][rg];
                }
        }
        // ---- PV: oacc += P . V  (V from pre-split VT, token-contiguous)
        #pragma unroll
        for (int k0 = 0; k0 < 2; k0++)
            #pragma unroll
            for (int mi = 0; mi < 2; mi++) {
                int prow = wm*32 + mi*16 + r;
                short8v ph = *(const short8v*)&PcH[prow*LP + k0*32 + q*8];
                short8v pl = *(const short8v*)&PcL[prow*LP + k0*32 + q*8];
                #pragma unroll
                for (int nd = 0; nd < 2; nd++) {
                    size_t vo = ((size_t)(wn*32 + nd*16 + r))*SEQ + tok0 + k0*32 + q*8;
                    short8v vh = *(const short8v*)(vH + vo);
                    short8v vl = *(const short8v*)(vL + vo);
                    oacc[mi][nd] = __builtin_amdgcn_mfma_f32_16x16x32_bf16(ph, vh, oacc[mi][nd], 0,0,0);
                    oacc[mi][nd] = __builtin_amdgcn_mfma_f32_16x16x32_bf16(ph, vl, oacc[mi][nd], 0,0,0);
                    oacc[mi][nd] = __builtin_amdgcn_mfma_f32_16x16x32_bf16(pl, vh, oacc[mi][nd], 0,0,0);
                }
            }
        __syncthreads();
    }
    // ---- write partials
    size_t pbase = ((size_t)g*NCH + ch)*MM + my*64;
    #pragma unroll
    for (int mi = 0; mi < 2; mi++)
        #pragma unroll
        for (int nd = 0; nd < 2; nd++)
            #pragma unroll
            for (int rg = 0; rg < 4; rg++) {
                int row = wm*32 + mi*16 + q*4 + rg;
                int col = wn*32 + nd*16 + r;
                PO[(pbase + row)*64 + col] = oacc[mi][nd][rg];
            }
    if (t < 64) {
        PM[pbase + t] = mrun[t];
        PL[pbase + t] = lrun[t];
    }
}

// ---------------------------------- combine flash partials -> A3VT (bf16 split)
__global__ __launch_bounds__(256)
void a3v_comb(const float* __restrict__ PO, const float* __restrict__ PM,
              const float* __restrict__ PL, ushort* __restrict__ oh, ushort* __restrict__ ol)
{
    int w = threadIdx.x >> 6, lane = threadIdx.x & 63;
    int gid = blockIdx.x * 4 + w;          // 0..4095
    int g = gid >> 8, rowm = gid & 255;
    size_t base = (size_t)g*NCH*MM + rowm;
    float m = -3.4e38f;
    #pragma unroll
    for (int ch = 0; ch < NCH; ch++) m = fmaxf(m, PM[base + (size_t)ch*MM]);
    float l = 0.f, o = 0.f;
    #pragma unroll
    for (int ch = 0; ch < NCH; ch++) {
        float f = __expf(PM[base + (size_t)ch*MM] - m);
        l += PL[base + (size_t)ch*MM] * f;
        o += PO[(base + (size_t)ch*MM)*64 + lane] * f;
    }
    float val = o / l;
    ushort hv = f2bf(val);
    size_t oo = (size_t)g*DH*MM + (size_t)lane*MM + rowm;
    oh[oo] = hv; ol[oo] = f2bf(val - bf2f(hv));
}

// --------------------------------------------- fused a1 (bf16 P in LDS)
// grid(SEQ/32, 16 slabs), 256 thr. Best measured 144-151us (R4). R2 (2x
// grid) and R5 (8 waves/block) both regressed: footprint/cache locality
// and per-barrier wave count dominate, not occupancy. DO NOT retune.
__global__ __launch_bounds__(256)
void a1_fused(const float* __restrict__ qkv,
              const ushort* __restrict__ klH, const ushort* __restrict__ klL,
              const ushort* __restrict__ wbH, const ushort* __restrict__ wbL,
              float* __restrict__ attn)
{
    constexpr int LP = 264;
    __shared__ ushort PcH[32*LP], PcL[32*LP];   // 16.5 KB each
    __shared__ float redm[4][32];
    __shared__ float reds[4][32];
    int g = blockIdx.y, b = g >> 3, h = g & 7;
    int tok0 = blockIdx.x * 32;
    int t = threadIdx.x;
    int w = t >> 6, lane = t & 63, q = lane >> 4, r = lane & 15;

    // ---- phase 1: S tile (32 tokens x 64 cols per wave)
    f32x4 acc[2][4];
    #pragma unroll
    for (int i = 0; i < 2; i++)
        #pragma unroll
        for (int j = 0; j < 4; j++) acc[i][j] = (f32x4){0.f,0.f,0.f,0.f};
    #pragma unroll
    for (int k0 = 0; k0 < 64; k0 += 32) {
        short8v ah[2], al[2];
        #pragma unroll
        for (int mi = 0; mi < 2; mi++) {
            const float* ap = qkv + ((size_t)b*SEQ + tok0 + mi*16 + r) * 1536
                            + h*DH + k0 + q*8;
            split8r(ap, ah[mi], al[mi]);
        }
        #pragma unroll
        for (int ni = 0; ni < 4; ni++) {
            size_t kb = ((size_t)g*MM + w*64 + ni*16 + r) * DH + k0 + q*8;
            short8v bh = *(const short8v*)(klH + kb);
            short8v bl = *(const short8v*)(klL + kb);
            #pragma unroll
            for (int mi = 0; mi < 2; mi++) {
                acc[mi][ni] = __builtin_amdgcn_mfma_f32_16x16x32_bf16(ah[mi], bh, acc[mi][ni], 0,0,0);
                acc[mi][ni] = __builtin_amdgcn_mfma_f32_16x16x32_bf16(ah[mi], bl, acc[mi][ni], 0,0,0);
                acc[mi][ni] = __builtin_amdgcn_mfma_f32_16x16x32_bf16(al[mi], bh, acc[mi][ni], 0,0,0);
            }
        }
    }
    // ---- row max (per wave, then cross-wave)
    #pragma unroll
    for (int mi = 0; mi < 2; mi++)
        #pragma unroll
        for (int rg = 0; rg < 4; rg++) {
            float m = fmaxf(fmaxf(acc[mi][0][rg], acc[mi][1][rg]),
                            fmaxf(acc[mi][2][rg], acc[mi][3][rg]));
            for (int o = 8; o > 0; o >>= 1) m = fmaxf(m, __shfl_xor(m, o));
            if (r == 0) redm[w][mi*16 + q*4 + rg] = m;
        }
    __syncthreads();
    // ---- exp (unnormalized, fast), partial sums; P -> bf16 hi/lo in LDS
    #pragma unroll
    for (int mi = 0; mi < 2; mi++)
        #pragma unroll
        for (int rg = 0; rg < 4; rg++) {
            int row = mi*16 + q*4 + rg;
            float gm = fmaxf(fmaxf(redm[0][row], redm[1][row]),
                             fmaxf(redm[2][row], redm[3][row]));
            float e0 = __expf(acc[mi][0][rg] - gm);
            float e1 = __expf(acc[mi][1][rg] - gm);
            float e2 = __expf(acc[mi][2][rg] - gm);
            float e3 = __expf(acc[mi][3][rg] - gm);
            float s = (e0 + e1) + (e2 + e3);
            unsigned h01 = cvt_pk_bf16(e0, e1);
            unsigned h23 = cvt_pk_bf16(e2, e3);
            float r0 = __uint_as_float(h01 << 16);
            float r1 = __uint_as_float(h01 & 0xFFFF0000u);
            float r2 = __uint_as_float(h23 << 16);
            float r3 = __uint_as_float(h23 & 0xFFFF0000u);
            unsigned l01 = cvt_pk_bf16(e0 - r0, e1 - r1);
            unsigned l23 = cvt_pk_bf16(e2 - r2, e3 - r3);
            int cb = row*LP + w*64 + r;
            PcH[cb     ] = (ushort)h01;
            PcH[cb + 16] = (ushort)(h01 >> 16);
            PcH[cb + 32] = (ushort)h23;
            PcH[cb + 48] = (ushort)(h23 >> 16);
            PcL[cb     ] = (ushort)l01;
            PcL[cb + 16] = (ushort)(l01 >> 16);
            PcL[cb + 32] = (ushort)l23;
            PcL[cb + 48] = (ushort)(l23 >> 16);
            for (int o = 8; o > 0; o >>= 1) s += __shfl_xor(s, o);
            if (r == 0) reds[w][row] = s;
        }
    __syncthreads();
    // ---- phase 2: wave (wm=w&1 row-half, wn=w>>1 d-half); K=256
    int wm = w & 1, wn = w >> 1;
    int prow = wm*16 + r;
    f32x4 oacc[2];
    #pragma unroll
    for (int ni = 0; ni < 2; ni++) oacc[ni] = (f32x4){0.f,0.f,0.f,0.f};
    #pragma unroll
    for (int k0 = 0; k0 < 8; k0++) {
        short8v ph = *(const short8v*)&PcH[prow*LP + k0*32 + q*8];
        short8v pl = *(const short8v*)&PcL[prow*LP + k0*32 + q*8];
        #pragma unroll
        for (int ni = 0; ni < 2; ni++) {
            size_t wo = ((size_t)g*64 + wn*32 + ni*16 + r) * MM + k0*32 + q*8;
            short8v bh = *(const short8v*)(wbH + wo);
            short8v bl = *(const short8v*)(wbL + wo);
            oacc[ni] = __builtin_amdgcn_mfma_f32_16x16x32_bf16(ph, bh, oacc[ni], 0,0,0);
            oacc[ni] = __builtin_amdgcn_mfma_f32_16x16x32_bf16(ph, bl, oacc[ni], 0,0,0);
            oacc[ni] = __builtin_amdgcn_mfma_f32_16x16x32_bf16(pl, bh, oacc[ni], 0,0,0);
        }
    }
    float inv[4];
    #pragma unroll
    for (int rg = 0; rg < 4; rg++) {
        int row = wm*16 + q*4 + rg;
        inv[rg] = 1.0f / (reds[0][row] + reds[1][row] + reds[2][row] + reds[3][row]);
    }
    #pragma unroll
    for (int ni = 0; ni < 2; ni++)
        #pragma unroll
        for (int rg = 0; rg < 4; rg++) {
            int tok = tok0 + wm*16 + q*4 + rg;
            attn[((size_t)b*SEQ + tok) * D + h*DH + wn*32 + ni*16 + r] = oacc[ni][rg] * inv[rg];
        }
}

// ---------------------------------- transpose + split fp32 (RxC) -> bf16 (CxR)
__global__ __launch_bounds__(256)
void convsplitT(const float* __restrict__ in, ushort* __restrict__ oh, ushort* __restrict__ ol,
                int R, int C, int ldin, long long sInB, long long sInH, long long sInZ,
                int ldo, long long sOutZ)
{
    __shared__ float tile[32][33];
    int z = blockIdx.z, b = z >> 3, h = z & 7;
    const float* I = in + (size_t)b*sInB + (size_t)h*sInH + (size_t)z*sInZ;
    int p0 = blockIdx.x * 32, c0 = blockIdx.y * 32;
    int tx = threadIdx.x & 31, ty = threadIdx.x >> 5;
    #pragma unroll
    for (int k = 0; k < 4; k++) {
        int rr = p0 + ty + k*8, cc = c0 + tx;
        tile[ty + k*8][tx] = (rr < R && cc < C) ? I[(size_t)rr * ldin + cc] : 0.f;
    }
    __syncthreads();
    #pragma unroll
    for (int k = 0; k < 4; k++) {
        int rr = p0 + tx, cc = c0 + ty + k*8;
        if (rr < R && cc < C) {
            float f = tile[tx][ty + k*8];
            ushort hv = f2bf(f);
            size_t o = (size_t)z * sOutZ + (size_t)cc * ldo + rr;
            oh[o] = hv; ol[o] = f2bf(f - bf2f(hv));
        }
    }
}

// ---------------------------------------------------------------- small ops
__global__ void fill_cls(const float* __restrict__ cls, float* __restrict__ H) {
    H[(size_t)blockIdx.x * NTOK * D + threadIdx.x] = cls[threadIdx.x];
}

// LayerNorm + pad; emits bf16 hi/lo pairs directly (bit-identical to the
// split the GEMM would apply to the same fp32 value) so the QKV GEMM can
// use pure-copy staging (mgemm128bb).
__global__ __launch_bounds__(256)
void ln_pad(const float* __restrict__ H, const float* __restrict__ g,
            const float* __restrict__ bt, ushort* __restrict__ outH,
            ushort* __restrict__ outL)
{
    int blk = blockIdx.x;
    int b = blk / SEQ, i = blk % SEQ;
    int t = threadIdx.x;
    ushort* ohr = outH + (size_t)blk * D;
    ushort* olr = outL + (size_t)blk * D;
    if (i < PADR) { ohr[t] = 0; ohr[t+256] = 0; olr[t] = 0; olr[t+256] = 0; return; }
    const float* x = H + ((size_t)b * NTOK + (i - PADR)) * D;
    float v0 = x[t], v1 = x[t+256];
    __shared__ float w1[4], w2[4];
    float s = v0 + v1;
    for (int o = 32; o > 0; o >>= 1) s += __shfl_xor(s, o);
    if ((t & 63) == 0) w1[t >> 6] = s;
    __syncthreads();
    float mu = (w1[0]+w1[1]+w1[2]+w1[3]) * (1.0f / D);
    float d0 = v0 - mu, d1 = v1 - mu;
    float qq = d0*d0 + d1*d1;
    for (int o = 32; o > 0; o >>= 1) qq += __shfl_xor(qq, o);
    if ((t & 63) == 0) w2[t >> 6] = qq;
    __syncthreads();
    float rs = rsqrtf((w2[0]+w2[1]+w2[2]+w2[3]) * (1.0f / D) + EPS_);
    float y0 = d0 * rs * g[t]     + bt[t];
    float y1 = d1 * rs * g[t+256] + bt[t+256];
    ushort h0 = f2bf(y0), h1 = f2bf(y1);
    ohr[t]     = h0; olr[t]     = f2bf(y0 - bf2f(h0));
    ohr[t+256] = h1; olr[t+256] = f2bf(y1 - bf2f(h1));
}

__global__ __launch_bounds__(512)
void landmarks(const float* __restrict__ qkv, float* __restrict__ ql,
               float* __restrict__ klt, ushort* __restrict__ klH, ushort* __restrict__ klL)
{
    int blk = blockIdx.x;
    int b = blk >> 8, m = blk & 255;
    int c = threadIdx.x;
    const float* base = qkv + ((size_t)b * SEQ + (size_t)m * LL) * 1536;
    float sq0=0,sq1=0,sq2=0,sq3=0, sk0=0,sk1=0,sk2=0,sk3=0;
    for (int tt = 0; tt < LL; tt += 4) {
        const float* rr = base + (size_t)tt * 1536;
        sq0 += rr[c];          sk0 += rr[512 + c];
        sq1 += rr[1536 + c];   sk1 += rr[1536 + 512 + c];
        sq2 += rr[3072 + c];   sk2 += rr[3072 + 512 + c];
        sq3 += rr[4608 + c];   sk3 += rr[4608 + 512 + c];
    }
    float sq = (sq0+sq1+sq2+sq3) * (1.0f / LL);
    float sk = (sk0+sk1+sk2+sk3) * (1.0f / LL);
    int h = c >> 6, d = c & 63;
    int slab = b * NH + h;
    ql [((size_t)slab * MM + m) * DH + d] = sq;
    klt[((size_t)slab * DH + d) * MM + m] = sk;
    size_t kidx = ((size_t)slab * MM + m) * DH + d;
    ushort kh = f2bf(sk);
    klH[kidx] = kh; klL[kidx] = f2bf(sk - bf2f(kh));
}

__global__ __launch_bounds__(256)
void s2_softmax(const float* __restrict__ ql, const float* __restrict__ klt,
                float* __restrict__ a2)
{
    int blk = blockIdx.x;
    int m = blk & 255, slab = blk >> 8;
    int j = threadIdx.x;
    __shared__ float q[64];
    __shared__ float red[256];
    if (j < 64) q[j] = ql[((size_t)slab * MM + m) * DH + j];
    __syncthreads();
    const float* kt = klt + (size_t)slab * DH * MM;
    float s = 0.f;
    #pragma unroll 8
    for (int kk = 0; kk < 64; kk++) s = fmaf(q[kk], kt[kk*MM + j], s);
    red[j] = s; __syncthreads();
    for (int o = 128; o > 0; o >>= 1) { if (j < o) red[j] = fmaxf(red[j], red[j+o]); __syncthreads(); }
    float mx = red[0]; __syncthreads();
    float e = __expf(s - mx);
    red[j] = e; __syncthreads();
    for (int o = 128; o > 0; o >>= 1) { if (j < o) red[j] += red[j+o]; __syncthreads(); }
    a2[((size_t)slab * MM + m) * MM + j] = e / red[0];
}

__global__ void zero_scr(float* s) { if (threadIdx.x < 2) s[threadIdx.x] = 0.f; }

__global__ __launch_bounds__(256)
void a2_alpha(const float* __restrict__ a2, float* __restrict__ scr)
{
    int slab = blockIdx.x, t = threadIdx.x;
    const float* A = a2 + (size_t)slab * MM * MM;
    float cs = 0.f, rs = 0.f;
    for (int rr = 0; rr < MM; rr++) cs += fabsf(A[(size_t)rr * MM + t]);
    for (int cc = 0; cc < MM; cc++) rs += fabsf(A[(size_t)t * MM + cc]);
    __shared__ float red[256];
    red[t] = rs; __syncthreads();
    for (int o = 128; o > 0; o >>= 1) { if (t < o) red[t] = fmaxf(red[t], red[t+o]); __syncthreads(); }
    float mrs = red[0]; __syncthreads();
    red[t] = cs; __syncthreads();
    for (int o = 128; o > 0; o >>= 1) { if (t < o) red[t] = fmaxf(red[t], red[t+o]); __syncthreads(); }
    float mcs = red[0];
    if (t == 0) { atomicMaxPosF(scr + 0, mrs); atomicMaxPosF(scr + 1, mcs); }
}

__global__ __launch_bounds__(256)
void z_init(const float* __restrict__ a2, const float* __restrict__ scr,
            float* __restrict__ z, ushort* __restrict__ zTh, ushort* __restrict__ zTl)
{
    size_t idx = (size_t)blockIdx.x * 256 + threadIdx.x;
    int slab = (int)(idx >> 16), rr = (int)((idx >> 8) & 255), cc = (int)(idx & 255);
    float inv = 1.0f / (scr[0] * scr[1]);
    z[idx] = a2[((size_t)slab << 16) + (size_t)cc * MM + rr] * inv;
    float tv = a2[idx] * inv;
    ushort th = f2bf(tv);
    zTh[idx] = th; zTl[idx] = f2bf(tv - bf2f(th));
}

__global__ __launch_bounds__(512)
void res_add(const float* __restrict__ qkv, const float* __restrict__ rw,
             float* __restrict__ attn)
{
    int blk = blockIdx.x;
    int b = blk / (SEQ/16), i0 = (blk % (SEQ/16)) * 16;
    int c = threadIdx.x, h = c >> 6;
    __shared__ float w[NH*33];
    if (c < NH*33) w[c] = rw[c];
    __syncthreads();
    float acc[16];
    float* ab = attn + ((size_t)b * SEQ + i0) * D + c;
    #pragma unroll
    for (int rr = 0; rr < 16; rr++) acc[rr] = ab[(size_t)rr * D];
    const float* vb = qkv + (size_t)b * SEQ * 1536 + 2*D + c;
    const float* wh = w + h * 33;
    #pragma unroll 4
    for (int jj = 0; jj < 48; jj++) {
        int j = i0 + jj - 16;
        float val = ((unsigned)j < (unsigned)SEQ) ? vb[(size_t)j * 1536] : 0.f;
        #pragma unroll
        for (int rr = 0; rr < 16; rr++) {
            int ky = jj - rr;
            if (ky >= 0 && ky < 33) acc[rr] = fmaf(val, wh[ky], acc[rr]);
        }
    }
    #pragma unroll
    for (int rr = 0; rr < 16; rr++) ab[(size_t)rr * D] = acc[rr];
}

// ---------------------------------------------------------------- PPEG
__global__ __launch_bounds__(256)
void t_fw(const float* __restrict__ H, float* __restrict__ P)
{
    __shared__ float tile[32][33];
    int p0 = blockIdx.x * 32, c0 = blockIdx.y * 32, b = blockIdx.z;
    int tx = threadIdx.x & 31, ty = threadIdx.x >> 5;
    #pragma unroll
    for (int k = 0; k < 4; k++) {
        int pos = p0 + ty + k*8;
        tile[ty + k*8][tx] = (pos < 10000)
            ? H[((size_t)b * NTOK + 1 + pos) * D + c0 + tx] : 0.f;
    }
    __syncthreads();
    #pragma unroll
    for (int k = 0; k < 4; k++) {
        int c = c0 + ty + k*8, pos = p0 + tx;
        if (pos < 10000)
            P[((size_t)b * D + c) * 10000 + pos] = tile[tx][ty + k*8];
    }
}

__global__ __launch_bounds__(256)
void ppeg_conv(const float* __restrict__ P,
               const float* __restrict__ w7, const float* __restrict__ b7,
               const float* __restrict__ w5, const float* __restrict__ b5,
               const float* __restrict__ w3, const float* __restrict__ b3,
               float* __restrict__ Q)
{
    __shared__ float PS[106 * 107];
    __shared__ float w7s[49], w5s[25], w3s[9];
    int blk = blockIdx.x;
    int b = blk >> 9, c = blk & 511;
    int t = threadIdx.x;
    for (int idx = t; idx < 106*107; idx += 256) PS[idx] = 0.f;
    if (t < 49) w7s[t] = w7[(size_t)c * 49 + t];
    if (t < 25) w5s[t] = w5[(size_t)c * 25 + t];
    if (t < 9)  w3s[t] = w3[(size_t)c * 9 + t];
    float bsum = b7[c] + b5[c] + b3[c];
    __syncthreads();
    const float* Pin = P + ((size_t)b * D + c) * 10000;
    for (int p = t; p < 10000; p += 256) {
        int y = p / 100, x = p - y * 100;
        PS[(y + 3) * 107 + x + 3] = Pin[p];
    }
    __syncthreads();
    float* Qo = Q + ((size_t)b * D + c) * 10000;
    for (int task = t; task < 2500; task += 256) {
        int ry = task / 100, x = task - ry * 100;
        int y0 = ry * 4;
        float a0 = bsum + PS[(y0+3)*107 + x+3];
        float a1 = bsum + PS[(y0+4)*107 + x+3];
        float a2 = bsum + PS[(y0+5)*107 + x+3];
        float a3 = bsum + PS[(y0+6)*107 + x+3];
        #pragma unroll
        for (int rr = 0; rr < 10; rr++) {
            const float* rp = &PS[(y0 + rr) * 107 + x];
            #pragma unroll
            for (int kx = 0; kx < 7; kx++) {
                float v = rp[kx];
                if (rr < 7)            a0 = fmaf(v, w7s[rr*7 + kx], a0);
                if (rr >= 1 && rr < 8) a1 = fmaf(v, w7s[(rr-1)*7 + kx], a1);
                if (rr >= 2 && rr < 9) a2 = fmaf(v, w7s[(rr-2)*7 + kx], a2);
                if (rr >= 3)           a3 = fmaf(v, w7s[(rr-3)*7 + kx], a3);
            }
        }
        #pragma unroll
        for (int rr = 0; rr < 8; rr++) {
            const float* rp = &PS[(y0 + rr + 1) * 107 + x + 1];
            #pragma unroll
            for (int kx = 0; kx < 5; kx++) {
                float v = rp[kx];
                if (rr < 5)            a0 = fmaf(v, w5s[rr*5 + kx], a0);
                if (rr >= 1 && rr < 6) a1 = fmaf(v, w5s[(rr-1)*5 + kx], a1);
                if (rr >= 2 && rr < 7) a2 = fmaf(v, w5s[(rr-2)*5 + kx], a2);
                if (rr >= 3)           a3 = fmaf(v, w5s[(rr-3)*5 + kx], a3);
            }
        }
        #pragma unroll
        for (int rr = 0; rr < 6; rr++) {
            const float* rp = &PS[(y0 + rr + 2) * 107 + x + 2];
            #pragma unroll
            for (int kx = 0; kx < 3; kx++) {
                float v = rp[kx];
                if (rr < 3)            a0 = fmaf(v, w3s[rr*3 + kx], a0);
                if (rr >= 1 && rr < 4) a1 = fmaf(v, w3s[(rr-1)*3 + kx], a1);
                if (rr >= 2 && rr < 5) a2 = fmaf(v, w3s[(rr-2)*3 + kx], a2);
                if (rr >= 3)           a3 = fmaf(v, w3s[(rr-3)*3 + kx], a3);
            }
        }
        Qo[(y0+0)*100 + x] = a0;
        Qo[(y0+1)*100 + x] = a1;
        Qo[(y0+2)*100 + x] = a2;
        Qo[(y0+3)*100 + x] = a3;
    }
}

__global__ __launch_bounds__(256)
void t_bw(const float* __restrict__ Q, float* __restrict__ H)
{
    __shared__ float tile[32][33];
    int p0 = blockIdx.x * 32, c0 = blockIdx.y * 32, b = blockIdx.z;
    int tx = threadIdx.x & 31, ty = threadIdx.x >> 5;
    #pragma unroll
    for (int k = 0; k < 4; k++) {
        int c = c0 + ty + k*8, pos = p0 + tx;
        tile[ty + k*8][tx] = (pos < 10000)
            ? Q[((size_t)b * D + c) * 10000 + pos] : 0.f;
    }
    __syncthreads();
    #pragma unroll
    for (int k = 0; k < 4; k++) {
        int pos = p0 + ty + k*8;
        if (pos < 10000)
            H[((size_t)b * NTOK + 1 + pos) * D + c0 + tx] = tile[tx][ty + k*8];
    }
}

__global__ __launch_bounds__(512)
void final_head(const float* __restrict__ H, const float* __restrict__ g,
                const float* __restrict__ bt, const float* __restrict__ w2,
                const float* __restrict__ b2, float* __restrict__ out)
{
    int b = blockIdx.x, t = threadIdx.x;
    __shared__ float red[512];
    float v = H[(size_t)b * NTOK * D + t];
    red[t] = v; __syncthreads();
    for (int o = 256; o > 0; o >>= 1) { if (t < o) red[t] += red[t+o]; __syncthreads(); }
    float mu = red[0] * (1.0f / D); __syncthreads();
    float dv = v - mu;
    red[t] = dv*dv; __syncthreads();
    for (int o = 256; o > 0; o >>= 1) { if (t < o) red[t] += red[t+o]; __syncthreads(); }
    float rstd = rsqrtf(red[0] * (1.0f / D) + EPS_); __syncthreads();
    float xn = dv * rstd * g[t] + bt[t];
    red[t] = xn * w2[2*t]; __syncthreads();
    for (int o = 256; o > 0; o >>= 1) { if (t < o) red[t] += red[t+o]; __syncthreads(); }
    float l0 = red[0] + b2[0]; __syncthreads();
    red[t] = xn * w2[2*t+1]; __syncthreads();
    for (int o = 256; o > 0; o >>= 1) { if (t < o) red[t] += red[t+o]; __syncthreads(); }
    float l1 = red[0] + b2[1];
    if (t == 0) {
        out[b*2+0] = l0; out[b*2+1] = l1;
        float mx = fmaxf(l0, l1);
        float e0 = expf(l0 - mx), e1 = expf(l1 - mx);
        float ssum = e0 + e1;
        out[4 + b*2 + 0] = e0 / ssum;
        out[4 + b*2 + 1] = e1 / ssum;
        out[8 + b] = (l1 > l0) ? 1.0f : 0.0f;
    }
}

// ---------------------------------------------------------------------------
extern "C" void kernel_launch(void* const* d_in, const int* in_sizes, int n_in,
                              void* d_out, int out_size, void* d_ws, size_t ws_size,
                              hipStream_t stream)
{
    const float* x      = (const float*)d_in[0];
    const float* w_fc1  = (const float*)d_in[1];
    const float* b_fc1  = (const float*)d_in[2];
    const float* cls    = (const float*)d_in[3];
    const float* ln1_g  = (const float*)d_in[4];
    const float* ln1_b  = (const float*)d_in[5];
    const float* qkv1_w = (const float*)d_in[6];
    const float* out1_w = (const float*)d_in[7];
    const float* out1_b = (const float*)d_in[8];
    const float* res1_w = (const float*)d_in[9];
    const float* ln2_g  = (const float*)d_in[10];
    const float* ln2_b  = (const float*)d_in[11];
    const float* qkv2_w = (const float*)d_in[12];
    const float* out2_w = (const float*)d_in[13];
    const float* out2_b = (const float*)d_in[14];
    const float* res2_w = (const float*)d_in[15];
    const float* pw7 = (const float*)d_in[16];
    const float* pb7 = (const float*)d_in[17];
    const float* pw5 = (const float*)d_in[18];
    const float* pb5 = (const float*)d_in[19];
    const float* pw3 = (const float*)d_in[20];
    const float* pb3 = (const float*)d_in[21];
    const float* lnf_g = (const float*)d_in[22];
    const float* lnf_b = (const float*)d_in[23];
    const float* w_fc2 = (const float*)d_in[24];
    const float* b_fc2 = (const float*)d_in[25];

    // workspace carve-up — R4-proven layout + 16 KB ROWM/ROWI (≈320.96 MB)
    float* ws = (float*)d_ws;
    size_t off = 0;
    auto alloc = [&](size_t n) { float* p = ws + off; off += (n + 63) & ~(size_t)63; return p; };
    float* H    = alloc((size_t)BB * NTOK * D);
    float* LN   = alloc((size_t)BB * SEQ * D);
    float* QKV  = alloc((size_t)BB * SEQ * 3 * D);
    float* QL   = alloc((size_t)BB * NH * MM * DH);
    float* KLT  = alloc((size_t)BB * NH * DH * MM);
    float* A2   = alloc((size_t)BB * NH * MM * MM);
    float* ZA   = alloc((size_t)BB * NH * MM * MM);
    float* ZB   = alloc((size_t)BB * NH * MM * MM);
    float* XZ   = alloc((size_t)BB * NH * MM * MM);
    float* A3V  = alloc((size_t)BB * NH * MM * DH);
    float* WB   = alloc((size_t)BB * NH * MM * DH);
    float* S3   = alloc((size_t)8 * MM * SEQ);
    float* SCR  = alloc(64);
    float* ROWM = alloc((size_t)8 * MM);
    float* ROWI = alloc((size_t)8 * MM);
    auto ualloc = [&](size_t n) { ushort* p = (ushort*)(ws + off); off += ((n + 127) / 2) & ~(size_t)63; return p; };
    ushort* WTfcH = ualloc((size_t)512 * 1024);
    ushort* WTfcL = ualloc((size_t)512 * 1024);
    ushort* WTqH  = ualloc((size_t)1536 * 512);
    ushort* WTqL  = ualloc((size_t)1536 * 512);
    ushort* WToH  = ualloc((size_t)512 * 512);
    ushort* WToL  = ualloc((size_t)512 * 512);
    ushort* klBH  = ualloc((size_t)16 * MM * DH);
    ushort* klBL  = ualloc((size_t)16 * MM * DH);
    float*  ATTN = LN;
    // LN region multi-use (serially): LNH/LNL (ln_pad -> QKV GEMM) then
    // VTH/VTL (convsplitT -> a3v) then ATTN (a1_fused -> out-proj).
    ushort* LNH  = (ushort*)LN;
    ushort* LNL  = LNH + (size_t)BB * SEQ * D;
    ushort* VTH  = (ushort*)LN;
    ushort* VTL  = VTH + (size_t)16 * DH * SEQ;
    ushort* A3VTH = (ushort*)ZB;
    ushort* A3VTL = A3VTH + (size_t)16 * DH * MM;
    ushort* WBTH  = A3VTL + (size_t)16 * DH * MM;
    ushort* WBTL  = WBTH  + (size_t)16 * DH * MM;
    ushort* PT   = (ushort*)S3;
    const size_t PS_ = (size_t)16 * 65536;
    ushort* zTAH = PT;            ushort* zTAL = PT + PS_;
    ushort* zTBH = PT + 2*PS_;    ushort* zTBL = PT + 3*PS_;
    ushort* XZTH = PT + 4*PS_;    ushort* XZTL = PT + 5*PS_;
    ushort* T1TH = PT + 6*PS_;    ushort* T1TL = PT + 7*PS_;
    ushort* T2TH = PT + 8*PS_;    ushort* T2TL = PT + 9*PS_;
    // S3 region layout (83.9 MB total), all serially dead vs each other:
    //   [0 .. 21 MB)   PT (NS transposes, dead after NS)
    //   [0 .. 34.6 MB) PO/PM/PL flash partials (written after NS)
    //   [34.6 .. 76.5) KsH/KsL pre-split K (written after QKV GEMM; no PT overlap)
    float* PO = S3;
    float* PM = S3 + (size_t)16 * NCH * MM * 64;
    float* PL = PM + (size_t)16 * NCH * MM;
    ushort* KsH = (ushort*)(PL + (size_t)16 * NCH * MM);
    ushort* KsL = KsH + (size_t)16 * SEQ * DH;
    (void)ws_size; (void)in_sizes; (void)n_in; (void)out_size;
    (void)A3V; (void)ROWM; (void)ROWI;

    // 0) fc1 weight prep + fc1 (batched over B via grid.z)
    convsplitT<<<dim3(32,16,1), 256, 0, stream>>>(w_fc1, WTfcH, WTfcL, 1024, 512, 512, 0,0,0, 1024, 0);
    mgemm128<<<dim3(4, 79, BB), 256, 0, stream>>>(x, DIN, (long long)N0*DIN,
        WTfcH, WTfcL, 1024, H + D, D, (long long)NTOK*D, b_fc1,
        N0, D, DIN, FLAG_BIAS|FLAG_RELU, 0, 1.f);
    fill_cls<<<BB, D, 0, stream>>>(cls, H);

    auto attention = [&](const float* lg, const float* lb,
                         const float* qw, const float* ow,
                         const float* ob, const float* rw)
    {
        convsplitT<<<dim3(16,48,1), 256, 0, stream>>>(qw, WTqH, WTqL, 512, 1536, 1536, 0,0,0, 512, 0);
        convsplitT<<<dim3(16,16,1), 256, 0, stream>>>(ow, WToH, WToL, 512, 512, 512, 0,0,0, 512, 0);
        ln_pad<<<BB*SEQ, 256, 0, stream>>>(H, lg, lb, LNH, LNL);
        mgemm128bb<<<dim3(12, 160, 1), 256, 0, stream>>>(LNH, LNL, D, WTqH, WTqL, D,
            QKV, 3*D, BB*SEQ, 3*D, D, D, 0.125f);
        convsplitT<<<dim3(320, 2, 16), 256, 0, stream>>>(QKV + 2*D, VTH, VTL,
            SEQ, DH, 1536, (long long)SEQ*1536, 64, 0, SEQ, (long long)DH*SEQ);
        ksplit<<<dim3(SEQ/16, 16), 256, 0, stream>>>(QKV, KsH, KsL);
        landmarks<<<BB*MM, 512, 0, stream>>>(QKV, QL, KLT, klBH, klBL);
        s2_softmax<<<BB*NH*MM, 256, 0, stream>>>(QL, KLT, A2);
        zero_scr<<<1, 64, 0, stream>>>(SCR);
        a2_alpha<<<BB*NH, 256, 0, stream>>>(A2, SCR);
        z_init<<<BB*NH*MM*MM/256, 256, 0, stream>>>(A2, SCR, ZA, zTAH, zTAL);
        // Newton-Schulz: 24 batched dispatches at 32x32 tiles (1024 blocks)
        float* z = ZA; float* zn = ZB;
        ushort *zTcH = zTAH, *zTcL = zTAL, *zTnH = zTBH, *zTnL = zTBL;
        for (int it = 0; it < 6; it++) {
            dim3 g(8, 8, 16);
            mbgemm32<<<g,256,0,stream>>>(A2, 65536LL, MM,
                zTcH, zTcL, 65536LL, MM,
                XZ, 65536LL, MM, XZTH, XZTL, 65536LL, MM,
                MM, 0.f, 1.f, 1.f);
            mbgemm32<<<g,256,0,stream>>>(XZ, 65536LL, MM,
                XZTH, XZTL, 65536LL, MM,
                nullptr, 0, MM, T1TH, T1TL, 65536LL, MM,
                MM, 7.f, -1.f, 1.f);
            mbgemm32<<<g,256,0,stream>>>(XZ, 65536LL, MM,
                T1TH, T1TL, 65536LL, MM,
                nullptr, 0, MM, T2TH, T2TL, 65536LL, MM,
                MM, 15.f, -1.f, 1.f);
            mbgemm32<<<g,256,0,stream>>>(z, 65536LL, MM,
                T2TH, T2TL, 65536LL, MM,
                zn, 65536LL, MM, zTnH, zTnL, 65536LL, MM,
                MM, 13.f, -1.f, 0.25f);
            float* ts = z; z = zn; zn = ts;
            ushort* uh = zTcH; zTcH = zTnH; zTnH = uh;
            ushort* ul = zTcL; zTcL = zTnL; zTnL = ul;
        }
        // z ends in ZA; PT region (in S3) now dead -> flash partials reuse S3
        a3v_flash<<<dim3(NCH, 4, 16), 256, 0, stream>>>(QL, KsH, KsL, VTH, VTL, PO, PM, PL);
        a3v_comb<<<dim3(16*MM/4), 256, 0, stream>>>(PO, PM, PL, A3VTH, A3VTL);
        // WB GEMM at 32x32 tiles
        mbgemm32<<<dim3(2, 8, 16), 256, 0, stream>>>(z, 65536LL, MM,
            A3VTH, A3VTL, 16384LL, MM,
            WB, 16384LL, DH, WBTH, WBTL, 16384LL, MM,
            MM, 0.f, 1.f, 1.f);
        // fused a1 (R4 version: 256 thr, pk-split softmax) - 144-151us proven
        a1_fused<<<dim3(SEQ/32, 16), 256, 0, stream>>>(QKV, klBH, klBL, WBTH, WBTL, ATTN);
        res_add<<<BB*SEQ/16, 512, 0, stream>>>(QKV, rw, ATTN);
        mgemm128<<<dim3(4, 79, BB), 256, 0, stream>>>(ATTN + (size_t)PADR*D, D, (long long)SEQ*D,
            WToH, WToL, D, H, D, (long long)NTOK*D, ob,
            NTOK, D, D, FLAG_BIAS|FLAG_ACC, 0, 1.f);
    };

    attention(ln1_g, ln1_b, qkv1_w, out1_w, out1_b, res1_w);

    {   // PPEG (planes inside S3 region)
        float* Pp = S3;
        float* Qp = S3 + (size_t)BB * D * 10000;
        dim3 tg((10000 + 31)/32, D/32, BB);
        t_fw<<<tg, 256, 0, stream>>>(H, Pp);
        ppeg_conv<<<BB*D, 256, 0, stream>>>(Pp, pw7, pb7, pw5, pb5, pw3, pb3, Qp);
        t_bw<<<tg, 256, 0, stream>>>(Qp, H);
    }

    attention(ln2_g, ln2_b, qkv2_w, out2_w, out2_b, res2_w);

    final_head<<<BB, 512, 0, stream>>>(H, lnf_g, lnf_b, w_fc2, b_fc2, (float*)d_out);
}

// Round 12
// 2107.880 us; speedup vs baseline: 1.0241x; 1.0241x over previous
//
#include <hip/hip_runtime.h>
#include <math.h>

#define FLAG_RELU 1
#define FLAG_BIAS 2
#define FLAG_ACC  4

static constexpr int BB   = 2;
static constexpr int N0   = 10000;
static constexpr int DIN  = 1024;
static constexpr int D    = 512;
static constexpr int NH   = 8;
static constexpr int DH   = 64;
static constexpr int MM   = 256;
static constexpr int SEQ  = 10240;
static constexpr int PADR = 239;
static constexpr int NTOK = 10001;
static constexpr int LL   = 40;
static constexpr int NCH  = 40;          // flash chunks per slab (R10-proven best)
static constexpr float EPS_ = 1e-5f;

typedef short short8v __attribute__((ext_vector_type(8)));
typedef float f32x4 __attribute__((ext_vector_type(4)));

__device__ __forceinline__ void atomicMaxPosF(float* addr, float v) {
    atomicMax((unsigned int*)addr, __float_as_uint(v));
}
__device__ __forceinline__ ushort f2bf(float f) {
    unsigned u = __float_as_uint(f);
    return (ushort)((u + 0x7FFFu + ((u >> 16) & 1u)) >> 16);
}
__device__ __forceinline__ float bf2f(ushort h) {
    return __uint_as_float(((unsigned)h) << 16);
}
// packed fp32x2 -> bf16x2 (RNE, identical to f2bf). low16 = cvt(s0).
__device__ __forceinline__ unsigned cvt_pk_bf16(float s0, float s1) {
    unsigned r;
    asm("v_cvt_pk_bf16_f32 %0, %1, %2" : "=v"(r) : "v"(s0), "v"(s1));
    return r;
}
struct bfs4 { unsigned h01, h23, l01, l23; };
__device__ __forceinline__ bfs4 split4pk(float4 f) {
    bfs4 o;
    o.h01 = cvt_pk_bf16(f.x, f.y);
    o.h23 = cvt_pk_bf16(f.z, f.w);
    float hx = __uint_as_float(o.h01 << 16);
    float hy = __uint_as_float(o.h01 & 0xFFFF0000u);
    float hz = __uint_as_float(o.h23 << 16);
    float hw = __uint_as_float(o.h23 & 0xFFFF0000u);
    o.l01 = cvt_pk_bf16(f.x - hx, f.y - hy);
    o.l23 = cvt_pk_bf16(f.z - hz, f.w - hw);
    return o;
}
__device__ __forceinline__ void split8r(const float* p, short8v& h, short8v& l) {
    float4 f0 = *(const float4*)p, f1 = *(const float4*)(p + 4);
    bfs4 a = split4pk(f0), b = split4pk(f1);
    uint4 hu = make_uint4(a.h01, a.h23, b.h01, b.h23);
    uint4 lu = make_uint4(a.l01, a.l23, b.l01, b.l23);
    h = *(short8v*)&hu; l = *(short8v*)&lu;
}

// ------------------------------------------------------- MFMA GEMM 128x128
__global__ __launch_bounds__(256)
void mgemm128(const float* __restrict__ A, int lda, long long sAz,
              const ushort* __restrict__ BtH, const ushort* __restrict__ BtL, int ldbt,
              float* __restrict__ C, int ldc, long long sCz, const float* __restrict__ bias,
              int M, int N, int K, int flags, int qcols, float qscale)
{
    __shared__ ushort AsH[4*128*8], AsL[4*128*8], BsH[4*128*8], BsL[4*128*8]; // 32 KB
    A += (size_t)blockIdx.z * sAz;
    C += (size_t)blockIdx.z * sCz;
    int t = threadIdx.x;
    int m0 = blockIdx.y * 128, n0 = blockIdx.x * 128;
    int w = t >> 6, lane = t & 63, q = lane >> 4, r = lane & 15;
    int wm = w >> 1, wn = w & 1;
    f32x4 acc[4][4];
    #pragma unroll
    for (int i = 0; i < 4; i++)
        #pragma unroll
        for (int j = 0; j < 4; j++) acc[i][j] = (f32x4){0.f,0.f,0.f,0.f};

    int srow = t >> 1, scg = (t & 1) * 16;
    int qg = (t & 1) * 2;
    int gm = m0 + srow;
    float4 pa0, pa1, pa2, pa3;
    uint4  pb0, pb1, pb2, pb3;
    {
        pa0 = pa1 = pa2 = pa3 = make_float4(0,0,0,0);
        if (gm < M) {
            const float* ap = A + (size_t)gm * lda + scg;
            pa0 = *(const float4*)(ap);   pa1 = *(const float4*)(ap+4);
            pa2 = *(const float4*)(ap+8); pa3 = *(const float4*)(ap+12);
        }
        size_t gb = (size_t)(n0 + srow) * ldbt + scg;
        pb0 = *(const uint4*)(BtH + gb); pb1 = *(const uint4*)(BtH + gb + 8);
        pb2 = *(const uint4*)(BtL + gb); pb3 = *(const uint4*)(BtL + gb + 8);
    }
    for (int k0 = 0; k0 < K; k0 += 32) {
        {
            bfs4 s0 = split4pk(pa0), s1 = split4pk(pa1);
            bfs4 s2 = split4pk(pa2), s3 = split4pk(pa3);
            *(uint4*)&AsH[(qg  )*1024 + srow*8] = make_uint4(s0.h01, s0.h23, s1.h01, s1.h23);
            *(uint4*)&AsH[(qg+1)*1024 + srow*8] = make_uint4(s2.h01, s2.h23, s3.h01, s3.h23);
            *(uint4*)&AsL[(qg  )*1024 + srow*8] = make_uint4(s0.l01, s0.l23, s1.l01, s1.l23);
            *(uint4*)&AsL[(qg+1)*1024 + srow*8] = make_uint4(s2.l01, s2.l23, s3.l01, s3.l23);
            *(uint4*)&BsH[(qg  )*1024 + srow*8] = pb0;
            *(uint4*)&BsH[(qg+1)*1024 + srow*8] = pb1;
            *(uint4*)&BsL[(qg  )*1024 + srow*8] = pb2;
            *(uint4*)&BsL[(qg+1)*1024 + srow*8] = pb3;
        }
        __syncthreads();
        if (k0 + 32 < K) {
            pa0 = pa1 = pa2 = pa3 = make_float4(0,0,0,0);
            if (gm < M) {
                const float* ap = A + (size_t)gm * lda + k0 + 32 + scg;
                pa0 = *(const float4*)(ap);   pa1 = *(const float4*)(ap+4);
                pa2 = *(const float4*)(ap+8); pa3 = *(const float4*)(ap+12);
            }
            size_t gb = (size_t)(n0 + srow) * ldbt + k0 + 32 + scg;
            pb0 = *(const uint4*)(BtH + gb); pb1 = *(const uint4*)(BtH + gb + 8);
            pb2 = *(const uint4*)(BtL + gb); pb3 = *(const uint4*)(BtL + gb + 8);
        }
        short8v ah[4], al[4];
        #pragma unroll
        for (int mi = 0; mi < 4; mi++) {
            int row = wm*64 + mi*16 + r;
            ah[mi] = *(const short8v*)&AsH[q*1024 + row*8];
            al[mi] = *(const short8v*)&AsL[q*1024 + row*8];
        }
        #pragma unroll
        for (int ni = 0; ni < 4; ni++) {
            int col = wn*64 + ni*16 + r;
            short8v bh = *(const short8v*)&BsH[q*1024 + col*8];
            short8v bl = *(const short8v*)&BsL[q*1024 + col*8];
            #pragma unroll
            for (int mi = 0; mi < 4; mi++) {
                acc[mi][ni] = __builtin_amdgcn_mfma_f32_16x16x32_bf16(ah[mi], bh, acc[mi][ni], 0,0,0);
                acc[mi][ni] = __builtin_amdgcn_mfma_f32_16x16x32_bf16(ah[mi], bl, acc[mi][ni], 0,0,0);
                acc[mi][ni] = __builtin_amdgcn_mfma_f32_16x16x32_bf16(al[mi], bh, acc[mi][ni], 0,0,0);
            }
        }
        __syncthreads();
    }
    #pragma unroll
    for (int mi = 0; mi < 4; mi++)
        #pragma unroll
        for (int ni = 0; ni < 4; ni++) {
            int gcol = n0 + wn*64 + ni*16 + r;
            float qs = (gcol < qcols) ? qscale : 1.f;
            float bv = (flags & FLAG_BIAS) ? bias[gcol] : 0.f;
            #pragma unroll
            for (int rg = 0; rg < 4; rg++) {
                int grow = m0 + wm*64 + mi*16 + q*4 + rg;
                if (grow >= M) continue;
                float v = acc[mi][ni][rg] * qs + bv;
                if (flags & FLAG_RELU) v = fmaxf(v, 0.f);
                float* cp = C + (size_t)grow * ldc + gcol;
                if (flags & FLAG_ACC) v += *cp;
                *cp = v;
            }
        }
}

// ----------------------------------- MFMA GEMM 128x128, BOTH operands pre-split
// For the QKV projection: A = LN pre-split by ln_pad (bit-identical to the
// split mgemm128 would apply to the same fp32 values). Staging is pure uint4
// copies -> removes the 12x-redundant per-n-block split VALU work.
__global__ __launch_bounds__(256)
void mgemm128bb(const ushort* __restrict__ AtH, const ushort* __restrict__ AtL, int lda,
                const ushort* __restrict__ BtH, const ushort* __restrict__ BtL, int ldbt,
                float* __restrict__ C, int ldc,
                int M, int N, int K, int qcols, float qscale)
{
    __shared__ ushort AsH[4*128*8], AsL[4*128*8], BsH[4*128*8], BsL[4*128*8]; // 32 KB
    int t = threadIdx.x;
    int m0 = blockIdx.y * 128, n0 = blockIdx.x * 128;
    int w = t >> 6, lane = t & 63, q = lane >> 4, r = lane & 15;
    int wm = w >> 1, wn = w & 1;
    f32x4 acc[4][4];
    #pragma unroll
    for (int i = 0; i < 4; i++)
        #pragma unroll
        for (int j = 0; j < 4; j++) acc[i][j] = (f32x4){0.f,0.f,0.f,0.f};

    int srow = t >> 1, scg = (t & 1) * 16;
    int qg = (t & 1) * 2;
    size_t ga = (size_t)(m0 + srow) * lda + scg;
    size_t gb = (size_t)(n0 + srow) * ldbt + scg;
    uint4 pa0, pa1, pa2, pa3, pb0, pb1, pb2, pb3;
    {
        pa0 = *(const uint4*)(AtH + ga); pa1 = *(const uint4*)(AtH + ga + 8);
        pa2 = *(const uint4*)(AtL + ga); pa3 = *(const uint4*)(AtL + ga + 8);
        pb0 = *(const uint4*)(BtH + gb); pb1 = *(const uint4*)(BtH + gb + 8);
        pb2 = *(const uint4*)(BtL + gb); pb3 = *(const uint4*)(BtL + gb + 8);
    }
    for (int k0 = 0; k0 < K; k0 += 32) {
        {
            *(uint4*)&AsH[(qg  )*1024 + srow*8] = pa0;
            *(uint4*)&AsH[(qg+1)*1024 + srow*8] = pa1;
            *(uint4*)&AsL[(qg  )*1024 + srow*8] = pa2;
            *(uint4*)&AsL[(qg+1)*1024 + srow*8] = pa3;
            *(uint4*)&BsH[(qg  )*1024 + srow*8] = pb0;
            *(uint4*)&BsH[(qg+1)*1024 + srow*8] = pb1;
            *(uint4*)&BsL[(qg  )*1024 + srow*8] = pb2;
            *(uint4*)&BsL[(qg+1)*1024 + srow*8] = pb3;
        }
        __syncthreads();
        if (k0 + 32 < K) {
            size_t ga2 = ga + k0 + 32;
            size_t gb2 = gb + k0 + 32;
            pa0 = *(const uint4*)(AtH + ga2); pa1 = *(const uint4*)(AtH + ga2 + 8);
            pa2 = *(const uint4*)(AtL + ga2); pa3 = *(const uint4*)(AtL + ga2 + 8);
            pb0 = *(const uint4*)(BtH + gb2); pb1 = *(const uint4*)(BtH + gb2 + 8);
            pb2 = *(const uint4*)(BtL + gb2); pb3 = *(const uint4*)(BtL + gb2 + 8);
        }
        short8v ah[4], al[4];
        #pragma unroll
        for (int mi = 0; mi < 4; mi++) {
            int row = wm*64 + mi*16 + r;
            ah[mi] = *(const short8v*)&AsH[q*1024 + row*8];
            al[mi] = *(const short8v*)&AsL[q*1024 + row*8];
        }
        #pragma unroll
        for (int ni = 0; ni < 4; ni++) {
            int col = wn*64 + ni*16 + r;
            short8v bh = *(const short8v*)&BsH[q*1024 + col*8];
            short8v bl = *(const short8v*)&BsL[q*1024 + col*8];
            #pragma unroll
            for (int mi = 0; mi < 4; mi++) {
                acc[mi][ni] = __builtin_amdgcn_mfma_f32_16x16x32_bf16(ah[mi], bh, acc[mi][ni], 0,0,0);
                acc[mi][ni] = __builtin_amdgcn_mfma_f32_16x16x32_bf16(ah[mi], bl, acc[mi][ni], 0,0,0);
                acc[mi][ni] = __builtin_amdgcn_mfma_f32_16x16x32_bf16(al[mi], bh, acc[mi][ni], 0,0,0);
            }
        }
        __syncthreads();
    }
    #pragma unroll
    for (int mi = 0; mi < 4; mi++)
        #pragma unroll
        for (int ni = 0; ni < 4; ni++) {
            int gcol = n0 + wn*64 + ni*16 + r;
            float qs = (gcol < qcols) ? qscale : 1.f;
            #pragma unroll
            for (int rg = 0; rg < 4; rg++) {
                int grow = m0 + wm*64 + mi*16 + q*4 + rg;
                C[(size_t)grow * ldc + gcol] = acc[mi][ni][rg] * qs;
            }
        }
}

// ------------------------------------------------------- MFMA batched 32x32
// Small-tile batched GEMM for the Newton-Schulz chain + WB GEMM (R6 win:
// 4x the block count of the 64x64 variant -> 4x occupancy on these small
// latency-bound GEMMs).
__global__ __launch_bounds__(256)
void mbgemm32(const float* __restrict__ Abase, long long sAz, int lda,
              const ushort* __restrict__ BtH, const ushort* __restrict__ BtL,
              long long sB, int ldb,
              float* __restrict__ Cbase, long long sC, int ldc,
              ushort* __restrict__ eTH, ushort* __restrict__ eTL, long long sT, int ldct,
              int K, float dg, float bsc, float osc)
{
    __shared__ ushort AsH[4*32*8], AsL[4*32*8], BsH[4*32*8], BsL[4*32*8]; // 8 KB
    int g = blockIdx.z;
    const float* A = Abase + (size_t)g * sAz;
    float* C = Cbase ? (Cbase + (size_t)g * sC) : nullptr;
    int t = threadIdx.x;
    int m0 = blockIdx.y * 32, n0 = blockIdx.x * 32;
    int w = t >> 6, lane = t & 63, q = lane >> 4, r = lane & 15;
    int wm = w >> 1, wn = w & 1;
    f32x4 acc = (f32x4){0.f,0.f,0.f,0.f};

    int srow = t >> 3, scg = (t & 7) * 4;
    int qg = scg >> 3, qo = scg & 4;
    float4 pa;
    uint2 pbh, pbl;
    {
        pa = *(const float4*)(A + (size_t)(m0 + srow) * lda + scg);
        size_t gb = (size_t)g*sB + (size_t)(n0 + srow) * ldb + scg;
        pbh = *(const uint2*)(BtH + gb); pbl = *(const uint2*)(BtL + gb);
    }
    for (int k0 = 0; k0 < K; k0 += 32) {
        {
            bfs4 s = split4pk(pa);
            *(uint2*)&AsH[qg*256 + srow*8 + qo] = make_uint2(s.h01, s.h23);
            *(uint2*)&AsL[qg*256 + srow*8 + qo] = make_uint2(s.l01, s.l23);
            *(uint2*)&BsH[qg*256 + srow*8 + qo] = pbh;
            *(uint2*)&BsL[qg*256 + srow*8 + qo] = pbl;
        }
        __syncthreads();
        if (k0 + 32 < K) {
            pa = *(const float4*)(A + (size_t)(m0 + srow) * lda + k0 + 32 + scg);
            size_t gb = (size_t)g*sB + (size_t)(n0 + srow) * ldb + k0 + 32 + scg;
            pbh = *(const uint2*)(BtH + gb); pbl = *(const uint2*)(BtL + gb);
        }
        short8v ah = *(const short8v*)&AsH[q*256 + (wm*16 + r)*8];
        short8v al = *(const short8v*)&AsL[q*256 + (wm*16 + r)*8];
        short8v bh = *(const short8v*)&BsH[q*256 + (wn*16 + r)*8];
        short8v bl = *(const short8v*)&BsL[q*256 + (wn*16 + r)*8];
        acc = __builtin_amdgcn_mfma_f32_16x16x32_bf16(ah, bh, acc, 0,0,0);
        acc = __builtin_amdgcn_mfma_f32_16x16x32_bf16(ah, bl, acc, 0,0,0);
        acc = __builtin_amdgcn_mfma_f32_16x16x32_bf16(al, bh, acc, 0,0,0);
        __syncthreads();
    }
    bool dgnz = (dg != 0.f);
    int gm0 = m0 + wm*16 + q*4;
    int gn  = n0 + wn*16 + r;
    float v[4];
    #pragma unroll
    for (int rg = 0; rg < 4; rg++) {
        float u = bsc * acc[rg];
        if (dgnz) u += dg * A[(size_t)(gm0+rg) * lda + gn];
        v[rg] = osc * u;
    }
    if (C) {
        #pragma unroll
        for (int rg = 0; rg < 4; rg++)
            C[(size_t)(gm0+rg) * ldc + gn] = v[rg];
    }
    if (eTH) {
        unsigned h01 = cvt_pk_bf16(v[0], v[1]);
        unsigned h23 = cvt_pk_bf16(v[2], v[3]);
        float h0 = __uint_as_float(h01 << 16);
        float h1 = __uint_as_float(h01 & 0xFFFF0000u);
        float h2 = __uint_as_float(h23 << 16);
        float h3 = __uint_as_float(h23 & 0xFFFF0000u);
        unsigned l01 = cvt_pk_bf16(v[0] - h0, v[1] - h1);
        unsigned l23 = cvt_pk_bf16(v[2] - h2, v[3] - h3);
        size_t to = (size_t)g * sT + (size_t)gn * ldct + gm0;
        *(uint2*)(eTH + to) = make_uint2(h01, h23);
        *(uint2*)(eTL + to) = make_uint2(l01, l23);
    }
}

// ---------------------------------------------- flash A3V (S3 never stored)
// R8: replaced the S3 materialize+maxsum+atomic-GEMM pipeline (-46us).
// R9: NCH 16->32 (-32us, occupancy 22.8%->~45%). R10: NCH=40 (-20us bundle).
// R11 NOTE: ksplit (pre-split K) + NCH=32 REGRESSED +47us -> this kernel is
// NOT K-load-bound; its cost is the serial phase chain (S-MFMA -> barrier ->
// softmax -> barrier -> PV). Inline K split stays; further gains need phase
// pipelining (high risk; R2/R5-class restructures both failed).
__global__ __launch_bounds__(256)
void a3v_flash(const float* __restrict__ ql, const float* __restrict__ qkv,
               const ushort* __restrict__ vtH, const ushort* __restrict__ vtL,
               float* __restrict__ PO, float* __restrict__ PM, float* __restrict__ PL)
{
    constexpr int LP  = 72;              // 64 + 8 pad (a1_fused's scheme)
    constexpr int CHT = SEQ / NCH;       // 256
    __shared__ ushort PcH[64*LP], PcL[64*LP];   // 9.2 KB each
    __shared__ float redm[2][64], reds[2][64];
    __shared__ float mrun[64], lrun[64];
    int ch = blockIdx.x, my = blockIdx.y, g = blockIdx.z;
    int b = g >> 3, h = g & 7;
    int t = threadIdx.x;
    int w = t >> 6, lane = t & 63, q = lane >> 4, r = lane & 15;
    int wm = w >> 1, wn = w & 1;

    if (t < 64) { mrun[t] = -3.4e38f; lrun[t] = 0.f; }

    // hoisted QL A-fragments (rows wm*32+mi*16+r, k = k0*32+q*8)
    short8v qh[2][2], qlo[2][2];
    #pragma unroll
    for (int mi = 0; mi < 2; mi++)
        #pragma unroll
        for (int k0 = 0; k0 < 2; k0++) {
            const float* ap = ql + ((size_t)g*MM + my*64 + wm*32 + mi*16 + r) * DH
                            + k0*32 + q*8;
            split8r(ap, qh[mi][k0], qlo[mi][k0]);
        }
    const float* Kb = qkv + (size_t)b*SEQ*1536 + D + h*DH;
    const ushort* vH = vtH + (size_t)g*DH*SEQ;
    const ushort* vL = vtL + (size_t)g*DH*SEQ;
    f32x4 oacc[2][2];
    #pragma unroll
    for (int i = 0; i < 2; i++)
        #pragma unroll
        for (int j = 0; j < 2; j++) oacc[i][j] = (f32x4){0.f,0.f,0.f,0.f};
    __syncthreads();

    for (int tt = 0; tt < CHT/64; tt++) {
        int tok0 = ch*CHT + tt*64;
        // ---- S tile: 64 rows x 64 tokens
        f32x4 sacc[2][2];
        #pragma unroll
        for (int i = 0; i < 2; i++)
            #pragma unroll
            for (int j = 0; j < 2; j++) sacc[i][j] = (f32x4){0.f,0.f,0.f,0.f};
        #pragma unroll
        for (int k0 = 0; k0 < 2; k0++)
            #pragma unroll
            for (int ni = 0; ni < 2; ni++) {
                short8v bh, bl;
                split8r(Kb + (size_t)(tok0 + wn*32 + ni*16 + r)*1536 + k0*32 + q*8, bh, bl);
                #pragma unroll
                for (int mi = 0; mi < 2; mi++) {
                    sacc[mi][ni] = __builtin_amdgcn_mfma_f32_16x16x32_bf16(qh[mi][k0], bh, sacc[mi][ni], 0,0,0);
                    sacc[mi][ni] = __builtin_amdgcn_mfma_f32_16x16x32_bf16(qh[mi][k0], bl, sacc[mi][ni], 0,0,0);
                    sacc[mi][ni] = __builtin_amdgcn_mfma_f32_16x16x32_bf16(qlo[mi][k0], bh, sacc[mi][ni], 0,0,0);
                }
            }
        // ---- tile row max
        #pragma unroll
        for (int mi = 0; mi < 2; mi++)
            #pragma unroll
            for (int rg = 0; rg < 4; rg++) {
                float m = fmaxf(sacc[mi][0][rg], sacc[mi][1][rg]);
                for (int o = 8; o > 0; o >>= 1) m = fmaxf(m, __shfl_xor(m, o));
                if (r == 0) redm[wn][wm*32 + mi*16 + q*4 + rg] = m;
            }
        __syncthreads();
        // ---- online update: P, partial sums, oacc rescale
        float scv[2][4], mnv[2][4];
        #pragma unroll
        for (int mi = 0; mi < 2; mi++)
            #pragma unroll
            for (int rg = 0; rg < 4; rg++) {
                int row = wm*32 + mi*16 + q*4 + rg;
                float tm = fmaxf(redm[0][row], redm[1][row]);
                float mo = mrun[row];
                float mn = fmaxf(mo, tm);
                float sc = __expf(mo - mn);
                scv[mi][rg] = sc; mnv[mi][rg] = mn;
                float e0 = __expf(sacc[mi][0][rg] - mn);
                float e1 = __expf(sacc[mi][1][rg] - mn);
                float s = e0 + e1;
                unsigned h01 = cvt_pk_bf16(e0, e1);
                float r0 = __uint_as_float(h01 << 16);
                float r1 = __uint_as_float(h01 & 0xFFFF0000u);
                unsigned l01 = cvt_pk_bf16(e0 - r0, e1 - r1);
                int cb = row*LP + wn*32 + r;
                PcH[cb     ] = (ushort)h01;
                PcH[cb + 16] = (ushort)(h01 >> 16);
                PcL[cb     ] = (ushort)l01;
                PcL[cb + 16] = (ushort)(l01 >> 16);
                oacc[mi][0][rg] *= sc;
                oacc[mi][1][rg] *= sc;
                for (int o = 8; o > 0; o >>= 1) s += __shfl_xor(s, o);
                if (r == 0) reds[wn][row] = s;
            }
        __syncthreads();
        if (wn == 0 && r == 0) {
            #pragma unroll
            for (int mi = 0; mi < 2; mi++)
                #pragma unroll
                for (int rg = 0; rg < 4; rg++) {
                    int row = wm*32 + mi*16 + q*4 + rg;
                    lrun[row] = lrun[row]*scv[mi][rg] + reds[0][row] + reds[1][row];
                    mrun[row] = mnv[mi][rg];
                }
        }
        // ---- PV: oacc += P . V  (V from pre-split VT, token-contiguous)
        #pragma unroll
        for (int k0 = 0; k0 < 2; k0++)
            #pragma unroll
            for (int mi = 0; mi < 2; mi++) {
                int prow = wm*32 + mi*16 + r;
                short8v ph = *(const short8v*)&PcH[prow*LP + k0*32 + q*8];
                short8v pl = *(const short8v*)&PcL[prow*LP + k0*32 + q*8];
                #pragma unroll
                for (int nd = 0; nd < 2; nd++) {
                    size_t vo = ((size_t)(wn*32 + nd*16 + r))*SEQ + tok0 + k0*32 + q*8;
                    short8v vh = *(const short8v*)(vH + vo);
                    short8v vl = *(const short8v*)(vL + vo);
                    oacc[mi][nd] = __builtin_amdgcn_mfma_f32_16x16x32_bf16(ph, vh, oacc[mi][nd], 0,0,0);
                    oacc[mi][nd] = __builtin_amdgcn_mfma_f32_16x16x32_bf16(ph, vl, oacc[mi][nd], 0,0,0);
                    oacc[mi][nd] = __builtin_amdgcn_mfma_f32_16x16x32_bf16(pl, vh, oacc[mi][nd], 0,0,0);
                }
            }
        __syncthreads();
    }
    // ---- write partials
    size_t pbase = ((size_t)g*NCH + ch)*MM + my*64;
    #pragma unroll
    for (int mi = 0; mi < 2; mi++)
        #pragma unroll
        for (int nd = 0; nd < 2; nd++)
            #pragma unroll
            for (int rg = 0; rg < 4; rg++) {
                int row = wm*32 + mi*16 + q*4 + rg;
                int col = wn*32 + nd*16 + r;
                PO[(pbase + row)*64 + col] = oacc[mi][nd][rg];
            }
    if (t < 64) {
        PM[pbase + t] = mrun[t];
        PL[pbase + t] = lrun[t];
    }
}

// ---------------------------------- combine flash partials -> A3VT (bf16 split)
__global__ __launch_bounds__(256)
void a3v_comb(const float* __restrict__ PO, const float* __restrict__ PM,
              const float* __restrict__ PL, ushort* __restrict__ oh, ushort* __restrict__ ol)
{
    int w = threadIdx.x >> 6, lane = threadIdx.x & 63;
    int gid = blockIdx.x * 4 + w;          // 0..4095
    int g = gid >> 8, rowm = gid & 255;
    size_t base = (size_t)g*NCH*MM + rowm;
    float m = -3.4e38f;
    #pragma unroll
    for (int ch = 0; ch < NCH; ch++) m = fmaxf(m, PM[base + (size_t)ch*MM]);
    float l = 0.f, o = 0.f;
    #pragma unroll
    for (int ch = 0; ch < NCH; ch++) {
        float f = __expf(PM[base + (size_t)ch*MM] - m);
        l += PL[base + (size_t)ch*MM] * f;
        o += PO[(base + (size_t)ch*MM)*64 + lane] * f;
    }
    float val = o / l;
    ushort hv = f2bf(val);
    size_t oo = (size_t)g*DH*MM + (size_t)lane*MM + rowm;
    oh[oo] = hv; ol[oo] = f2bf(val - bf2f(hv));
}

// --------------------------------------------- fused a1 (bf16 P in LDS)
// grid(SEQ/32, 16 slabs), 256 thr. Best measured 144-151us (R4). R2 (2x
// grid) and R5 (8 waves/block) both regressed: footprint/cache locality
// and per-barrier wave count dominate, not occupancy. DO NOT retune.
__global__ __launch_bounds__(256)
void a1_fused(const float* __restrict__ qkv,
              const ushort* __restrict__ klH, const ushort* __restrict__ klL,
              const ushort* __restrict__ wbH, const ushort* __restrict__ wbL,
              float* __restrict__ attn)
{
    constexpr int LP = 264;
    __shared__ ushort PcH[32*LP], PcL[32*LP];   // 16.5 KB each
    __shared__ float redm[4][32];
    __shared__ float reds[4][32];
    int g = blockIdx.y, b = g >> 3, h = g & 7;
    int tok0 = blockIdx.x * 32;
    int t = threadIdx.x;
    int w = t >> 6, lane = t & 63, q = lane >> 4, r = lane & 15;

    // ---- phase 1: S tile (32 tokens x 64 cols per wave)
    f32x4 acc[2][4];
    #pragma unroll
    for (int i = 0; i < 2; i++)
        #pragma unroll
        for (int j = 0; j < 4; j++) acc[i][j] = (f32x4){0.f,0.f,0.f,0.f};
    #pragma unroll
    for (int k0 = 0; k0 < 64; k0 += 32) {
        short8v ah[2], al[2];
        #pragma unroll
        for (int mi = 0; mi < 2; mi++) {
            const float* ap = qkv + ((size_t)b*SEQ + tok0 + mi*16 + r) * 1536
                            + h*DH + k0 + q*8;
            split8r(ap, ah[mi], al[mi]);
        }
        #pragma unroll
        for (int ni = 0; ni < 4; ni++) {
            size_t kb = ((size_t)g*MM + w*64 + ni*16 + r) * DH + k0 + q*8;
            short8v bh = *(const short8v*)(klH + kb);
            short8v bl = *(const short8v*)(klL + kb);
            #pragma unroll
            for (int mi = 0; mi < 2; mi++) {
                acc[mi][ni] = __builtin_amdgcn_mfma_f32_16x16x32_bf16(ah[mi], bh, acc[mi][ni], 0,0,0);
                acc[mi][ni] = __builtin_amdgcn_mfma_f32_16x16x32_bf16(ah[mi], bl, acc[mi][ni], 0,0,0);
                acc[mi][ni] = __builtin_amdgcn_mfma_f32_16x16x32_bf16(al[mi], bh, acc[mi][ni], 0,0,0);
            }
        }
    }
    // ---- row max (per wave, then cross-wave)
    #pragma unroll
    for (int mi = 0; mi < 2; mi++)
        #pragma unroll
        for (int rg = 0; rg < 4; rg++) {
            float m = fmaxf(fmaxf(acc[mi][0][rg], acc[mi][1][rg]),
                            fmaxf(acc[mi][2][rg], acc[mi][3][rg]));
            for (int o = 8; o > 0; o >>= 1) m = fmaxf(m, __shfl_xor(m, o));
            if (r == 0) redm[w][mi*16 + q*4 + rg] = m;
        }
    __syncthreads();
    // ---- exp (unnormalized, fast), partial sums; P -> bf16 hi/lo in LDS
    #pragma unroll
    for (int mi = 0; mi < 2; mi++)
        #pragma unroll
        for (int rg = 0; rg < 4; rg++) {
            int row = mi*16 + q*4 + rg;
            float gm = fmaxf(fmaxf(redm[0][row], redm[1][row]),
                             fmaxf(redm[2][row], redm[3][row]));
            float e0 = __expf(acc[mi][0][rg] - gm);
            float e1 = __expf(acc[mi][1][rg] - gm);
            float e2 = __expf(acc[mi][2][rg] - gm);
            float e3 = __expf(acc[mi][3][rg] - gm);
            float s = (e0 + e1) + (e2 + e3);
            unsigned h01 = cvt_pk_bf16(e0, e1);
            unsigned h23 = cvt_pk_bf16(e2, e3);
            float r0 = __uint_as_float(h01 << 16);
            float r1 = __uint_as_float(h01 & 0xFFFF0000u);
            float r2 = __uint_as_float(h23 << 16);
            float r3 = __uint_as_float(h23 & 0xFFFF0000u);
            unsigned l01 = cvt_pk_bf16(e0 - r0, e1 - r1);
            unsigned l23 = cvt_pk_bf16(e2 - r2, e3 - r3);
            int cb = row*LP + w*64 + r;
            PcH[cb     ] = (ushort)h01;
            PcH[cb + 16] = (ushort)(h01 >> 16);
            PcH[cb + 32] = (ushort)h23;
            PcH[cb + 48] = (ushort)(h23 >> 16);
            PcL[cb     ] = (ushort)l01;
            PcL[cb + 16] = (ushort)(l01 >> 16);
            PcL[cb + 32] = (ushort)l23;
            PcL[cb + 48] = (ushort)(l23 >> 16);
            for (int o = 8; o > 0; o >>= 1) s += __shfl_xor(s, o);
            if (r == 0) reds[w][row] = s;
        }
    __syncthreads();
    // ---- phase 2: wave (wm=w&1 row-half, wn=w>>1 d-half); K=256
    int wm = w & 1, wn = w >> 1;
    int prow = wm*16 + r;
    f32x4 oacc[2];
    #pragma unroll
    for (int ni = 0; ni < 2; ni++) oacc[ni] = (f32x4){0.f,0.f,0.f,0.f};
    #pragma unroll
    for (int k0 = 0; k0 < 8; k0++) {
        short8v ph = *(const short8v*)&PcH[prow*LP + k0*32 + q*8];
        short8v pl = *(const short8v*)&PcL[prow*LP + k0*32 + q*8];
        #pragma unroll
        for (int ni = 0; ni < 2; ni++) {
            size_t wo = ((size_t)g*64 + wn*32 + ni*16 + r) * MM + k0*32 + q*8;
            short8v bh = *(const short8v*)(wbH + wo);
            short8v bl = *(const short8v*)(wbL + wo);
            oacc[ni] = __builtin_amdgcn_mfma_f32_16x16x32_bf16(ph, bh, oacc[ni], 0,0,0);
            oacc[ni] = __builtin_amdgcn_mfma_f32_16x16x32_bf16(ph, bl, oacc[ni], 0,0,0);
            oacc[ni] = __builtin_amdgcn_mfma_f32_16x16x32_bf16(pl, bh, oacc[ni], 0,0,0);
        }
    }
    float inv[4];
    #pragma unroll
    for (int rg = 0; rg < 4; rg++) {
        int row = wm*16 + q*4 + rg;
        inv[rg] = 1.0f / (reds[0][row] + reds[1][row] + reds[2][row] + reds[3][row]);
    }
    #pragma unroll
    for (int ni = 0; ni < 2; ni++)
        #pragma unroll
        for (int rg = 0; rg < 4; rg++) {
            int tok = tok0 + wm*16 + q*4 + rg;
            attn[((size_t)b*SEQ + tok) * D + h*DH + wn*32 + ni*16 + r] = oacc[ni][rg] * inv[rg];
        }
}

// ---------------------------------- transpose + split fp32 (RxC) -> bf16 (CxR)
__global__ __launch_bounds__(256)
void convsplitT(const float* __restrict__ in, ushort* __restrict__ oh, ushort* __restrict__ ol,
                int R, int C, int ldin, long long sInB, long long sInH, long long sInZ,
                int ldo, long long sOutZ)
{
    __shared__ float tile[32][33];
    int z = blockIdx.z, b = z >> 3, h = z & 7;
    const float* I = in + (size_t)b*sInB + (size_t)h*sInH + (size_t)z*sInZ;
    int p0 = blockIdx.x * 32, c0 = blockIdx.y * 32;
    int tx = threadIdx.x & 31, ty = threadIdx.x >> 5;
    #pragma unroll
    for (int k = 0; k < 4; k++) {
        int rr = p0 + ty + k*8, cc = c0 + tx;
        tile[ty + k*8][tx] = (rr < R && cc < C) ? I[(size_t)rr * ldin + cc] : 0.f;
    }
    __syncthreads();
    #pragma unroll
    for (int k = 0; k < 4; k++) {
        int rr = p0 + tx, cc = c0 + ty + k*8;
        if (rr < R && cc < C) {
            float f = tile[tx][ty + k*8];
            ushort hv = f2bf(f);
            size_t o = (size_t)z * sOutZ + (size_t)cc * ldo + rr;
            oh[o] = hv; ol[o] = f2bf(f - bf2f(hv));
        }
    }
}

// ---------------------------------------------------------------- small ops
__global__ void fill_cls(const float* __restrict__ cls, float* __restrict__ H) {
    H[(size_t)blockIdx.x * NTOK * D + threadIdx.x] = cls[threadIdx.x];
}

// LayerNorm + pad; emits bf16 hi/lo pairs directly (bit-identical to the
// split the GEMM would apply to the same fp32 value) so the QKV GEMM can
// use pure-copy staging (mgemm128bb).
__global__ __launch_bounds__(256)
void ln_pad(const float* __restrict__ H, const float* __restrict__ g,
            const float* __restrict__ bt, ushort* __restrict__ outH,
            ushort* __restrict__ outL)
{
    int blk = blockIdx.x;
    int b = blk / SEQ, i = blk % SEQ;
    int t = threadIdx.x;
    ushort* ohr = outH + (size_t)blk * D;
    ushort* olr = outL + (size_t)blk * D;
    if (i < PADR) { ohr[t] = 0; ohr[t+256] = 0; olr[t] = 0; olr[t+256] = 0; return; }
    const float* x = H + ((size_t)b * NTOK + (i - PADR)) * D;
    float v0 = x[t], v1 = x[t+256];
    __shared__ float w1[4], w2[4];
    float s = v0 + v1;
    for (int o = 32; o > 0; o >>= 1) s += __shfl_xor(s, o);
    if ((t & 63) == 0) w1[t >> 6] = s;
    __syncthreads();
    float mu = (w1[0]+w1[1]+w1[2]+w1[3]) * (1.0f / D);
    float d0 = v0 - mu, d1 = v1 - mu;
    float qq = d0*d0 + d1*d1;
    for (int o = 32; o > 0; o >>= 1) qq += __shfl_xor(qq, o);
    if ((t & 63) == 0) w2[t >> 6] = qq;
    __syncthreads();
    float rs = rsqrtf((w2[0]+w2[1]+w2[2]+w2[3]) * (1.0f / D) + EPS_);
    float y0 = d0 * rs * g[t]     + bt[t];
    float y1 = d1 * rs * g[t+256] + bt[t+256];
    ushort h0 = f2bf(y0), h1 = f2bf(y1);
    ohr[t]     = h0; olr[t]     = f2bf(y0 - bf2f(h0));
    ohr[t+256] = h1; olr[t+256] = f2bf(y1 - bf2f(h1));
}

__global__ __launch_bounds__(512)
void landmarks(const float* __restrict__ qkv, float* __restrict__ ql,
               float* __restrict__ klt, ushort* __restrict__ klH, ushort* __restrict__ klL)
{
    int blk = blockIdx.x;
    int b = blk >> 8, m = blk & 255;
    int c = threadIdx.x;
    const float* base = qkv + ((size_t)b * SEQ + (size_t)m * LL) * 1536;
    float sq0=0,sq1=0,sq2=0,sq3=0, sk0=0,sk1=0,sk2=0,sk3=0;
    for (int tt = 0; tt < LL; tt += 4) {
        const float* rr = base + (size_t)tt * 1536;
        sq0 += rr[c];          sk0 += rr[512 + c];
        sq1 += rr[1536 + c];   sk1 += rr[1536 + 512 + c];
        sq2 += rr[3072 + c];   sk2 += rr[3072 + 512 + c];
        sq3 += rr[4608 + c];   sk3 += rr[4608 + 512 + c];
    }
    float sq = (sq0+sq1+sq2+sq3) * (1.0f / LL);
    float sk = (sk0+sk1+sk2+sk3) * (1.0f / LL);
    int h = c >> 6, d = c & 63;
    int slab = b * NH + h;
    ql [((size_t)slab * MM + m) * DH + d] = sq;
    klt[((size_t)slab * DH + d) * MM + m] = sk;
    size_t kidx = ((size_t)slab * MM + m) * DH + d;
    ushort kh = f2bf(sk);
    klH[kidx] = kh; klL[kidx] = f2bf(sk - bf2f(kh));
}

__global__ __launch_bounds__(256)
void s2_softmax(const float* __restrict__ ql, const float* __restrict__ klt,
                float* __restrict__ a2)
{
    int blk = blockIdx.x;
    int m = blk & 255, slab = blk >> 8;
    int j = threadIdx.x;
    __shared__ float q[64];
    __shared__ float red[256];
    if (j < 64) q[j] = ql[((size_t)slab * MM + m) * DH + j];
    __syncthreads();
    const float* kt = klt + (size_t)slab * DH * MM;
    float s = 0.f;
    #pragma unroll 8
    for (int kk = 0; kk < 64; kk++) s = fmaf(q[kk], kt[kk*MM + j], s);
    red[j] = s; __syncthreads();
    for (int o = 128; o > 0; o >>= 1) { if (j < o) red[j] = fmaxf(red[j], red[j+o]); __syncthreads(); }
    float mx = red[0]; __syncthreads();
    float e = __expf(s - mx);
    red[j] = e; __syncthreads();
    for (int o = 128; o > 0; o >>= 1) { if (j < o) red[j] += red[j+o]; __syncthreads(); }
    a2[((size_t)slab * MM + m) * MM + j] = e / red[0];
}

__global__ void zero_scr(float* s) { if (threadIdx.x < 2) s[threadIdx.x] = 0.f; }

__global__ __launch_bounds__(256)
void a2_alpha(const float* __restrict__ a2, float* __restrict__ scr)
{
    int slab = blockIdx.x, t = threadIdx.x;
    const float* A = a2 + (size_t)slab * MM * MM;
    float cs = 0.f, rs = 0.f;
    for (int rr = 0; rr < MM; rr++) cs += fabsf(A[(size_t)rr * MM + t]);
    for (int cc = 0; cc < MM; cc++) rs += fabsf(A[(size_t)t * MM + cc]);
    __shared__ float red[256];
    red[t] = rs; __syncthreads();
    for (int o = 128; o > 0; o >>= 1) { if (t < o) red[t] = fmaxf(red[t], red[t+o]); __syncthreads(); }
    float mrs = red[0]; __syncthreads();
    red[t] = cs; __syncthreads();
    for (int o = 128; o > 0; o >>= 1) { if (t < o) red[t] = fmaxf(red[t], red[t+o]); __syncthreads(); }
    float mcs = red[0];
    if (t == 0) { atomicMaxPosF(scr + 0, mrs); atomicMaxPosF(scr + 1, mcs); }
}

__global__ __launch_bounds__(256)
void z_init(const float* __restrict__ a2, const float* __restrict__ scr,
            float* __restrict__ z, ushort* __restrict__ zTh, ushort* __restrict__ zTl)
{
    size_t idx = (size_t)blockIdx.x * 256 + threadIdx.x;
    int slab = (int)(idx >> 16), rr = (int)((idx >> 8) & 255), cc = (int)(idx & 255);
    float inv = 1.0f / (scr[0] * scr[1]);
    z[idx] = a2[((size_t)slab << 16) + (size_t)cc * MM + rr] * inv;
    float tv = a2[idx] * inv;
    ushort th = f2bf(tv);
    zTh[idx] = th; zTl[idx] = f2bf(tv - bf2f(th));
}

__global__ __launch_bounds__(512)
void res_add(const float* __restrict__ qkv, const float* __restrict__ rw,
             float* __restrict__ attn)
{
    int blk = blockIdx.x;
    int b = blk / (SEQ/16), i0 = (blk % (SEQ/16)) * 16;
    int c = threadIdx.x, h = c >> 6;
    __shared__ float w[NH*33];
    if (c < NH*33) w[c] = rw[c];
    __syncthreads();
    float acc[16];
    float* ab = attn + ((size_t)b * SEQ + i0) * D + c;
    #pragma unroll
    for (int rr = 0; rr < 16; rr++) acc[rr] = ab[(size_t)rr * D];
    const float* vb = qkv + (size_t)b * SEQ * 1536 + 2*D + c;
    const float* wh = w + h * 33;
    #pragma unroll 4
    for (int jj = 0; jj < 48; jj++) {
        int j = i0 + jj - 16;
        float val = ((unsigned)j < (unsigned)SEQ) ? vb[(size_t)j * 1536] : 0.f;
        #pragma unroll
        for (int rr = 0; rr < 16; rr++) {
            int ky = jj - rr;
            if (ky >= 0 && ky < 33) acc[rr] = fmaf(val, wh[ky], acc[rr]);
        }
    }
    #pragma unroll
    for (int rr = 0; rr < 16; rr++) ab[(size_t)rr * D] = acc[rr];
}

// ---------------------------------------------------------------- PPEG
__global__ __launch_bounds__(256)
void t_fw(const float* __restrict__ H, float* __restrict__ P)
{
    __shared__ float tile[32][33];
    int p0 = blockIdx.x * 32, c0 = blockIdx.y * 32, b = blockIdx.z;
    int tx = threadIdx.x & 31, ty = threadIdx.x >> 5;
    #pragma unroll
    for (int k = 0; k < 4; k++) {
        int pos = p0 + ty + k*8;
        tile[ty + k*8][tx] = (pos < 10000)
            ? H[((size_t)b * NTOK + 1 + pos) * D + c0 + tx] : 0.f;
    }
    __syncthreads();
    #pragma unroll
    for (int k = 0; k < 4; k++) {
        int c = c0 + ty + k*8, pos = p0 + tx;
        if (pos < 10000)
            P[((size_t)b * D + c) * 10000 + pos] = tile[tx][ty + k*8];
    }
}

__global__ __launch_bounds__(256)
void ppeg_conv(const float* __restrict__ P,
               const float* __restrict__ w7, const float* __restrict__ b7,
               const float* __restrict__ w5, const float* __restrict__ b5,
               const float* __restrict__ w3, const float* __restrict__ b3,
               float* __restrict__ Q)
{
    __shared__ float PS[106 * 107];
    __shared__ float w7s[49], w5s[25], w3s[9];
    int blk = blockIdx.x;
    int b = blk >> 9, c = blk & 511;
    int t = threadIdx.x;
    for (int idx = t; idx < 106*107; idx += 256) PS[idx] = 0.f;
    if (t < 49) w7s[t] = w7[(size_t)c * 49 + t];
    if (t < 25) w5s[t] = w5[(size_t)c * 25 + t];
    if (t < 9)  w3s[t] = w3[(size_t)c * 9 + t];
    float bsum = b7[c] + b5[c] + b3[c];
    __syncthreads();
    const float* Pin = P + ((size_t)b * D + c) * 10000;
    for (int p = t; p < 10000; p += 256) {
        int y = p / 100, x = p - y * 100;
        PS[(y + 3) * 107 + x + 3] = Pin[p];
    }
    __syncthreads();
    float* Qo = Q + ((size_t)b * D + c) * 10000;
    for (int task = t; task < 2500; task += 256) {
        int ry = task / 100, x = task - ry * 100;
        int y0 = ry * 4;
        float a0 = bsum + PS[(y0+3)*107 + x+3];
        float a1 = bsum + PS[(y0+4)*107 + x+3];
        float a2 = bsum + PS[(y0+5)*107 + x+3];
        float a3 = bsum + PS[(y0+6)*107 + x+3];
        #pragma unroll
        for (int rr = 0; rr < 10; rr++) {
            const float* rp = &PS[(y0 + rr) * 107 + x];
            #pragma unroll
            for (int kx = 0; kx < 7; kx++) {
                float v = rp[kx];
                if (rr < 7)            a0 = fmaf(v, w7s[rr*7 + kx], a0);
                if (rr >= 1 && rr < 8) a1 = fmaf(v, w7s[(rr-1)*7 + kx], a1);
                if (rr >= 2 && rr < 9) a2 = fmaf(v, w7s[(rr-2)*7 + kx], a2);
                if (rr >= 3)           a3 = fmaf(v, w7s[(rr-3)*7 + kx], a3);
            }
        }
        #pragma unroll
        for (int rr = 0; rr < 8; rr++) {
            const float* rp = &PS[(y0 + rr + 1) * 107 + x + 1];
            #pragma unroll
            for (int kx = 0; kx < 5; kx++) {
                float v = rp[kx];
                if (rr < 5)            a0 = fmaf(v, w5s[rr*5 + kx], a0);
                if (rr >= 1 && rr < 6) a1 = fmaf(v, w5s[(rr-1)*5 + kx], a1);
                if (rr >= 2 && rr < 7) a2 = fmaf(v, w5s[(rr-2)*5 + kx], a2);
                if (rr >= 3)           a3 = fmaf(v, w5s[(rr-3)*5 + kx], a3);
            }
        }
        #pragma unroll
        for (int rr = 0; rr < 6; rr++) {
            const float* rp = &PS[(y0 + rr + 2) * 107 + x + 2];
            #pragma unroll
            for (int kx = 0; kx < 3; kx++) {
                float v = rp[kx];
                if (rr < 3)            a0 = fmaf(v, w3s[rr*3 + kx], a0);
                if (rr >= 1 && rr < 4) a1 = fmaf(v, w3s[(rr-1)*3 + kx], a1);
                if (rr >= 2 && rr < 5) a2 = fmaf(v, w3s[(rr-2)*3 + kx], a2);
                if (rr >= 3)           a3 = fmaf(v, w3s[(rr-3)*3 + kx], a3);
            }
        }
        Qo[(y0+0)*100 + x] = a0;
        Qo[(y0+1)*100 + x] = a1;
        Qo[(y0+2)*100 + x] = a2;
        Qo[(y0+3)*100 + x] = a3;
    }
}

__global__ __launch_bounds__(256)
void t_bw(const float* __restrict__ Q, float* __restrict__ H)
{
    __shared__ float tile[32][33];
    int p0 = blockIdx.x * 32, c0 = blockIdx.y * 32, b = blockIdx.z;
    int tx = threadIdx.x & 31, ty = threadIdx.x >> 5;
    #pragma unroll
    for (int k = 0; k < 4; k++) {
        int c = c0 + ty + k*8, pos = p0 + tx;
        tile[ty + k*8][tx] = (pos < 10000)
            ? Q[((size_t)b * D + c) * 10000 + pos] : 0.f;
    }
    __syncthreads();
    #pragma unroll
    for (int k = 0; k < 4; k++) {
        int pos = p0 + ty + k*8;
        if (pos < 10000)
            H[((size_t)b * NTOK + 1 + pos) * D + c0 + tx] = tile[tx][ty + k*8];
    }
}

__global__ __launch_bounds__(512)
void final_head(const float* __restrict__ H, const float* __restrict__ g,
                const float* __restrict__ bt, const float* __restrict__ w2,
                const float* __restrict__ b2, float* __restrict__ out)
{
    int b = blockIdx.x, t = threadIdx.x;
    __shared__ float red[512];
    float v = H[(size_t)b * NTOK * D + t];
    red[t] = v; __syncthreads();
    for (int o = 256; o > 0; o >>= 1) { if (t < o) red[t] += red[t+o]; __syncthreads(); }
    float mu = red[0] * (1.0f / D); __syncthreads();
    float dv = v - mu;
    red[t] = dv*dv; __syncthreads();
    for (int o = 256; o > 0; o >>= 1) { if (t < o) red[t] += red[t+o]; __syncthreads(); }
    float rstd = rsqrtf(red[0] * (1.0f / D) + EPS_); __syncthreads();
    float xn = dv * rstd * g[t] + bt[t];
    red[t] = xn * w2[2*t]; __syncthreads();
    for (int o = 256; o > 0; o >>= 1) { if (t < o) red[t] += red[t+o]; __syncthreads(); }
    float l0 = red[0] + b2[0]; __syncthreads();
    red[t] = xn * w2[2*t+1]; __syncthreads();
    for (int o = 256; o > 0; o >>= 1) { if (t < o) red[t] += red[t+o]; __syncthreads(); }
    float l1 = red[0] + b2[1];
    if (t == 0) {
        out[b*2+0] = l0; out[b*2+1] = l1;
        float mx = fmaxf(l0, l1);
        float e0 = expf(l0 - mx), e1 = expf(l1 - mx);
        float ssum = e0 + e1;
        out[4 + b*2 + 0] = e0 / ssum;
        out[4 + b*2 + 1] = e1 / ssum;
        out[8 + b] = (l1 > l0) ? 1.0f : 0.0f;
    }
}

// ---------------------------------------------------------------------------
extern "C" void kernel_launch(void* const* d_in, const int* in_sizes, int n_in,
                              void* d_out, int out_size, void* d_ws, size_t ws_size,
                              hipStream_t stream)
{
    const float* x      = (const float*)d_in[0];
    const float* w_fc1  = (const float*)d_in[1];
    const float* b_fc1  = (const float*)d_in[2];
    const float* cls    = (const float*)d_in[3];
    const float* ln1_g  = (const float*)d_in[4];
    const float* ln1_b  = (const float*)d_in[5];
    const float* qkv1_w = (const float*)d_in[6];
    const float* out1_w = (const float*)d_in[7];
    const float* out1_b = (const float*)d_in[8];
    const float* res1_w = (const float*)d_in[9];
    const float* ln2_g  = (const float*)d_in[10];
    const float* ln2_b  = (const float*)d_in[11];
    const float* qkv2_w = (const float*)d_in[12];
    const float* out2_w = (const float*)d_in[13];
    const float* out2_b = (const float*)d_in[14];
    const float* res2_w = (const float*)d_in[15];
    const float* pw7 = (const float*)d_in[16];
    const float* pb7 = (const float*)d_in[17];
    const float* pw5 = (const float*)d_in[18];
    const float* pb5 = (const float*)d_in[19];
    const float* pw3 = (const float*)d_in[20];
    const float* pb3 = (const float*)d_in[21];
    const float* lnf_g = (const float*)d_in[22];
    const float* lnf_b = (const float*)d_in[23];
    const float* w_fc2 = (const float*)d_in[24];
    const float* b_fc2 = (const float*)d_in[25];

    // workspace carve-up — R4-proven layout + 16 KB ROWM/ROWI (≈320.96 MB)
    float* ws = (float*)d_ws;
    size_t off = 0;
    auto alloc = [&](size_t n) { float* p = ws + off; off += (n + 63) & ~(size_t)63; return p; };
    float* H    = alloc((size_t)BB * NTOK * D);
    float* LN   = alloc((size_t)BB * SEQ * D);
    float* QKV  = alloc((size_t)BB * SEQ * 3 * D);
    float* QL   = alloc((size_t)BB * NH * MM * DH);
    float* KLT  = alloc((size_t)BB * NH * DH * MM);
    float* A2   = alloc((size_t)BB * NH * MM * MM);
    float* ZA   = alloc((size_t)BB * NH * MM * MM);
    float* ZB   = alloc((size_t)BB * NH * MM * MM);
    float* XZ   = alloc((size_t)BB * NH * MM * MM);
    float* A3V  = alloc((size_t)BB * NH * MM * DH);
    float* WB   = alloc((size_t)BB * NH * MM * DH);
    float* S3   = alloc((size_t)8 * MM * SEQ);
    float* SCR  = alloc(64);
    float* ROWM = alloc((size_t)8 * MM);
    float* ROWI = alloc((size_t)8 * MM);
    auto ualloc = [&](size_t n) { ushort* p = (ushort*)(ws + off); off += ((n + 127) / 2) & ~(size_t)63; return p; };
    ushort* WTfcH = ualloc((size_t)512 * 1024);
    ushort* WTfcL = ualloc((size_t)512 * 1024);
    ushort* WTqH  = ualloc((size_t)1536 * 512);
    ushort* WTqL  = ualloc((size_t)1536 * 512);
    ushort* WToH  = ualloc((size_t)512 * 512);
    ushort* WToL  = ualloc((size_t)512 * 512);
    ushort* klBH  = ualloc((size_t)16 * MM * DH);
    ushort* klBL  = ualloc((size_t)16 * MM * DH);
    float*  ATTN = LN;
    // LN region multi-use (serially): LNH/LNL (ln_pad -> QKV GEMM) then
    // VTH/VTL (convsplitT -> a3v) then ATTN (a1_fused -> out-proj).
    ushort* LNH  = (ushort*)LN;
    ushort* LNL  = LNH + (size_t)BB * SEQ * D;
    ushort* VTH  = (ushort*)LN;
    ushort* VTL  = VTH + (size_t)16 * DH * SEQ;
    ushort* A3VTH = (ushort*)ZB;
    ushort* A3VTL = A3VTH + (size_t)16 * DH * MM;
    ushort* WBTH  = A3VTL + (size_t)16 * DH * MM;
    ushort* WBTL  = WBTH  + (size_t)16 * DH * MM;
    ushort* PT   = (ushort*)S3;
    const size_t PS_ = (size_t)16 * 65536;
    ushort* zTAH = PT;            ushort* zTAL = PT + PS_;
    ushort* zTBH = PT + 2*PS_;    ushort* zTBL = PT + 3*PS_;
    ushort* XZTH = PT + 4*PS_;    ushort* XZTL = PT + 5*PS_;
    ushort* T1TH = PT + 6*PS_;    ushort* T1TL = PT + 7*PS_;
    ushort* T2TH = PT + 8*PS_;    ushort* T2TL = PT + 9*PS_;
    // flash partials: live in S3 region (dead after NS; S3 never materialized
    // now). PO 41.9 MB + PM/PL 1.3 MB << 84 MB.
    float* PO = S3;
    float* PM = S3 + (size_t)16 * NCH * MM * 64;
    float* PL = PM + (size_t)16 * NCH * MM;
    (void)ws_size; (void)in_sizes; (void)n_in; (void)out_size;
    (void)A3V; (void)ROWM; (void)ROWI;

    // 0) fc1 weight prep + fc1 (batched over B via grid.z)
    convsplitT<<<dim3(32,16,1), 256, 0, stream>>>(w_fc1, WTfcH, WTfcL, 1024, 512, 512, 0,0,0, 1024, 0);
    mgemm128<<<dim3(4, 79, BB), 256, 0, stream>>>(x, DIN, (long long)N0*DIN,
        WTfcH, WTfcL, 1024, H + D, D, (long long)NTOK*D, b_fc1,
        N0, D, DIN, FLAG_BIAS|FLAG_RELU, 0, 1.f);
    fill_cls<<<BB, D, 0, stream>>>(cls, H);

    auto attention = [&](const float* lg, const float* lb,
                         const float* qw, const float* ow,
                         const float* ob, const float* rw)
    {
        convsplitT<<<dim3(16,48,1), 256, 0, stream>>>(qw, WTqH, WTqL, 512, 1536, 1536, 0,0,0, 512, 0);
        convsplitT<<<dim3(16,16,1), 256, 0, stream>>>(ow, WToH, WToL, 512, 512, 512, 0,0,0, 512, 0);
        ln_pad<<<BB*SEQ, 256, 0, stream>>>(H, lg, lb, LNH, LNL);
        mgemm128bb<<<dim3(12, 160, 1), 256, 0, stream>>>(LNH, LNL, D, WTqH, WTqL, D,
            QKV, 3*D, BB*SEQ, 3*D, D, D, 0.125f);
        convsplitT<<<dim3(320, 2, 16), 256, 0, stream>>>(QKV + 2*D, VTH, VTL,
            SEQ, DH, 1536, (long long)SEQ*1536, 64, 0, SEQ, (long long)DH*SEQ);
        landmarks<<<BB*MM, 512, 0, stream>>>(QKV, QL, KLT, klBH, klBL);
        s2_softmax<<<BB*NH*MM, 256, 0, stream>>>(QL, KLT, A2);
        zero_scr<<<1, 64, 0, stream>>>(SCR);
        a2_alpha<<<BB*NH, 256, 0, stream>>>(A2, SCR);
        z_init<<<BB*NH*MM*MM/256, 256, 0, stream>>>(A2, SCR, ZA, zTAH, zTAL);
        // Newton-Schulz: 24 batched dispatches at 32x32 tiles (1024 blocks)
        float* z = ZA; float* zn = ZB;
        ushort *zTcH = zTAH, *zTcL = zTAL, *zTnH = zTBH, *zTnL = zTBL;
        for (int it = 0; it < 6; it++) {
            dim3 g(8, 8, 16);
            mbgemm32<<<g,256,0,stream>>>(A2, 65536LL, MM,
                zTcH, zTcL, 65536LL, MM,
                XZ, 65536LL, MM, XZTH, XZTL, 65536LL, MM,
                MM, 0.f, 1.f, 1.f);
            mbgemm32<<<g,256,0,stream>>>(XZ, 65536LL, MM,
                XZTH, XZTL, 65536LL, MM,
                nullptr, 0, MM, T1TH, T1TL, 65536LL, MM,
                MM, 7.f, -1.f, 1.f);
            mbgemm32<<<g,256,0,stream>>>(XZ, 65536LL, MM,
                T1TH, T1TL, 65536LL, MM,
                nullptr, 0, MM, T2TH, T2TL, 65536LL, MM,
                MM, 15.f, -1.f, 1.f);
            mbgemm32<<<g,256,0,stream>>>(z, 65536LL, MM,
                T2TH, T2TL, 65536LL, MM,
                zn, 65536LL, MM, zTnH, zTnL, 65536LL, MM,
                MM, 13.f, -1.f, 0.25f);
            float* ts = z; z = zn; zn = ts;
            ushort* uh = zTcH; zTcH = zTnH; zTnH = uh;
            ushort* ul = zTcL; zTcL = zTnL; zTnL = ul;
        }
        // z ends in ZA; PT region (in S3) now dead -> flash partials reuse S3
        a3v_flash<<<dim3(NCH, 4, 16), 256, 0, stream>>>(QL, QKV, VTH, VTL, PO, PM, PL);
        a3v_comb<<<dim3(16*MM/4), 256, 0, stream>>>(PO, PM, PL, A3VTH, A3VTL);
        // WB GEMM at 32x32 tiles
        mbgemm32<<<dim3(2, 8, 16), 256, 0, stream>>>(z, 65536LL, MM,
            A3VTH, A3VTL, 16384LL, MM,
            WB, 16384LL, DH, WBTH, WBTL, 16384LL, MM,
            MM, 0.f, 1.f, 1.f);
        // fused a1 (R4 version: 256 thr, pk-split softmax) - 144-151us proven
        a1_fused<<<dim3(SEQ/32, 16), 256, 0, stream>>>(QKV, klBH, klBL, WBTH, WBTL, ATTN);
        res_add<<<BB*SEQ/16, 512, 0, stream>>>(QKV, rw, ATTN);
        mgemm128<<<dim3(4, 79, BB), 256, 0, stream>>>(ATTN + (size_t)PADR*D, D, (long long)SEQ*D,
            WToH, WToL, D, H, D, (long long)NTOK*D, ob,
            NTOK, D, D, FLAG_BIAS|FLAG_ACC, 0, 1.f);
    };

    attention(ln1_g, ln1_b, qkv1_w, out1_w, out1_b, res1_w);

    {   // PPEG (planes inside S3 region)
        float* Pp = S3;
        float* Qp = S3 + (size_t)BB * D * 10000;
        dim3 tg((10000 + 31)/32, D/32, BB);
        t_fw<<<tg, 256, 0, stream>>>(H, Pp);
        ppeg_conv<<<BB*D, 256, 0, stream>>>(Pp, pw7, pb7, pw5, pb5, pw3, pb3, Qp);
        t_bw<<<tg, 256, 0, stream>>>(Qp, H);
    }

    attention(ln2_g, ln2_b, qkv2_w, out2_w, out2_b, res2_w);

    final_head<<<BB, 512, 0, stream>>>(H, lnf_g, lnf_b, w_fc2, b_fc2, (float*)d_out);
}